// Round 2
// baseline (315.766 us; speedup 1.0000x reference)
//
#include <hip/hip_runtime.h>
#include <math.h>

#define BDIM 8
#define MDIM 1024
#define CDIM 768
#define ROWS (BDIM * MDIM)   // 8192

typedef __attribute__((ext_vector_type(8))) short short8;   // 8 bf16
typedef __attribute__((ext_vector_type(8))) unsigned short ushort8;
typedef __attribute__((ext_vector_type(4))) float f32x4;

#define MFMA16(a, b, c) __builtin_amdgcn_mfma_f32_16x16x32_bf16((a), (b), (c), 0, 0, 0)

#define BAR() __builtin_amdgcn_s_barrier()
#define FENCE() asm volatile("" ::: "memory")
#define SCHED_FENCE() __builtin_amdgcn_sched_barrier(0)
#define WAIT_LGKM0() asm volatile("s_waitcnt lgkmcnt(0)" ::: "memory")
#define WAIT_VM6() asm volatile("s_waitcnt vmcnt(6)" ::: "memory")
#define WAIT_VM0() asm volatile("s_waitcnt vmcnt(0)" ::: "memory")

__device__ __forceinline__ unsigned short f2bf(float f) {
  unsigned u = __float_as_uint(f);
  return (unsigned short)((u + 0x7FFFu + ((u >> 16) & 1u)) >> 16);
}

// ---------------------------------------------------------------------------
// Prologue (one launch): input converts + weight transpose-converts.
// Flat grid of 10176 blocks x 256 threads:
//   [0,3072): convert layout_x; [3072,6144): convert text_x;
//   [6144,10176): transpose_w (168x24).
// ---------------------------------------------------------------------------
__global__ __launch_bounds__(256) void prologue(
    const float* __restrict__ xl, const float* __restrict__ xt,
    unsigned short* __restrict__ dxl, unsigned short* __restrict__ dxt,
    const float* __restrict__ W0, const float* __restrict__ W1,
    const float* __restrict__ W2, const float* __restrict__ W3,
    unsigned short* __restrict__ D0, unsigned short* __restrict__ D1,
    unsigned short* __restrict__ D2, unsigned short* __restrict__ D3) {
  const int bx = blockIdx.x;
  const int tid = threadIdx.x;
  if (bx < 6144) {
    const float* src = bx < 3072 ? xl : xt;
    unsigned short* dst = bx < 3072 ? dxl : dxt;
    const int i = ((bx < 3072 ? bx : bx - 3072) * 256 + tid) * 8;
    const float4 a = *(const float4*)(src + i);
    const float4 b = *(const float4*)(src + i + 4);
    ushort8 o;
    o[0] = f2bf(a.x); o[1] = f2bf(a.y); o[2] = f2bf(a.z); o[3] = f2bf(a.w);
    o[4] = f2bf(b.x); o[5] = f2bf(b.y); o[6] = f2bf(b.z); o[7] = f2bf(b.w);
    *(ushort8*)(dst + i) = o;
  } else {
    int x = bx - 6144;
    int bxx = x % 168;
    const int k0 = (x / 168) * 32;
    const float* W; unsigned short* D; int N;
    if (bxx < 72)       { W = W0; D = D0; N = 2304; }
    else if (bxx < 96)  { W = W1; D = D1; N = 768;  bxx -= 72; }
    else if (bxx < 144) { W = W2; D = D2; N = 1536; bxx -= 96; }
    else                { W = W3; D = D3; N = 768;  bxx -= 144; }
    __shared__ unsigned short t[32][33];
    const int tx = tid & 31, ty = tid >> 5;
    const int n0 = bxx * 32;
#pragma unroll
    for (int i = 0; i < 4; ++i)
      t[ty + i * 8][tx] = f2bf(W[(size_t)(k0 + ty + i * 8) * N + n0 + tx]);
    __syncthreads();
#pragma unroll
    for (int i = 0; i < 4; ++i)
      D[(size_t)(n0 + ty + i * 8) * CDIM + k0 + tx] = t[tx][ty + i * 8];
  }
}

// ---------------------------------------------------------------------------
// BK=64 MFMA engine (128x128 tile, 2-barrier structure) — kept for the
// attention-middle kernels and the small cq projection.
// ---------------------------------------------------------------------------
__device__ __forceinline__ void stage64(
    const unsigned short* __restrict__ g, int ld, int k0,
    unsigned short* lds, int wave, int lane) {
  const int gchunk = (lane & 7) ^ (lane >> 3);
#pragma unroll
  for (int j = 0; j < 4; ++j) {
    const int grp = wave * 4 + j;
    const unsigned short* gp =
        g + (size_t)(grp * 8 + (lane >> 3)) * ld + k0 + gchunk * 8;
    __builtin_amdgcn_global_load_lds(
        (const __attribute__((address_space(1))) unsigned int*)gp,
        (__attribute__((address_space(3))) unsigned int*)(lds + grp * 512),
        16, 0, 0);
  }
}

__device__ __forceinline__ void mfma_loop64(
    const unsigned short* __restrict__ A, int lda,
    const unsigned short* __restrict__ Bt, int ldb, int K,
    unsigned short* As, unsigned short* Bs, f32x4 acc[4][4],
    int wave, int lane) {
  const int wx = wave & 1, wy = wave >> 1;
  const int quad = lane >> 4, l16 = lane & 15;
  for (int k0 = 0; k0 < K; k0 += 64) {
    stage64(A, lda, k0, As, wave, lane);
    stage64(Bt, ldb, k0, Bs, wave, lane);
    __syncthreads();
#pragma unroll
    for (int h = 0; h < 2; ++h) {
      const int slot = ((((h << 2) | quad) ^ (l16 & 7))) * 8;
      short8 afr[4], bfr[4];
#pragma unroll
      for (int mt = 0; mt < 4; ++mt)
        afr[mt] = *(const short8*)&As[(wy * 64 + mt * 16 + l16) * 64 + slot];
#pragma unroll
      for (int nt = 0; nt < 4; ++nt)
        bfr[nt] = *(const short8*)&Bs[(wx * 64 + nt * 16 + l16) * 64 + slot];
#pragma unroll
      for (int mt = 0; mt < 4; ++mt)
#pragma unroll
        for (int nt = 0; nt < 4; ++nt)
          acc[mt][nt] = MFMA16(afr[mt], bfr[nt], acc[mt][nt]);
    }
    __syncthreads();
  }
}

// Projection epilogue for the 128x128 engine (slice-routed bf16 write).
__device__ __forceinline__ void proj_epilogue(
    f32x4 acc[4][4], const float* __restrict__ bias,
    unsigned short* __restrict__ Y, unsigned short* __restrict__ vTd,
    int c0, int m0, int lastSlice, int trans, int wave, int lane) {
  const int wx = wave & 1, wy = wave >> 1;
  const int quad = lane >> 4, l16 = lane & 15;
  const int slice = c0 / 768;
  if (trans && slice == lastSlice) {
#pragma unroll
    for (int mt = 0; mt < 4; ++mt) {
      const int row0 = m0 + wy * 64 + mt * 16 + quad * 4;
      const int b = row0 >> 10, n0 = row0 & 1023;
#pragma unroll
      for (int nt = 0; nt < 4; ++nt) {
        const int gcol = c0 + wx * 64 + nt * 16 + l16;
        const int d = gcol - slice * 768;
        const float bv = bias[gcol];
        uint2 o;
        o.x = (unsigned)f2bf(acc[mt][nt][0] + bv) |
              ((unsigned)f2bf(acc[mt][nt][1] + bv) << 16);
        o.y = (unsigned)f2bf(acc[mt][nt][2] + bv) |
              ((unsigned)f2bf(acc[mt][nt][3] + bv) << 16);
        *(uint2*)&vTd[((size_t)b * CDIM + d) * MDIM + n0] = o;
      }
    }
  } else {
    const size_t sbase = (size_t)slice * ROWS * 768;
#pragma unroll
    for (int mt = 0; mt < 4; ++mt)
#pragma unroll
      for (int nt = 0; nt < 4; ++nt) {
        const int gcol = c0 + wx * 64 + nt * 16 + l16;
        const int lcol = gcol - slice * 768;
        const float bv = bias[gcol];
#pragma unroll
        for (int rg = 0; rg < 4; ++rg) {
          const int row = m0 + wy * 64 + mt * 16 + quad * 4 + rg;
          Y[sbase + (size_t)row * 768 + lcol] = f2bf(acc[mt][nt][rg] + bv);
        }
      }
  }
}

// XCD-swizzled block mapping for (gx, 64) 128x128 grids.
__device__ __forceinline__ void swizzle_mc(int lin, int* m0, int* c0) {
  const int xcd = lin & 7, j = lin >> 3;
  *m0 = (xcd * 8 + (j & 7)) * 128;
  *c0 = (j >> 3) * 128;
}

// ---------------------------------------------------------------------------
// 256x256 8-phase engine (T2 swizzle + T3/T4 counted vmcnt + T5 setprio).
// 512 threads = 8 waves (2M x 4N); per-wave output 128x64; BK=64; 12 K-tiles
// (K=768). LDS 128 KiB: 2 dbuf x {A0,A1,B0,B1} halves of [128][64] bf16,
// chunk-XOR swizzled. Schedule per K-tile t (buf c=t&1, n=c^1):
//   p0: dsread A0,B0(c); stage A1(t+1)->n;  BAR; lgkm0; 16 MFMA (0,0); BAR
//   p1: dsread B1(c);    stage A0(t+2)->c;  BAR; lgkm0; 16 MFMA (0,1); BAR
//   p2: dsread A1(c);    stage B0(t+2)->c;  BAR; lgkm0; 16 MFMA (1,0); BAR
//   p3:                  stage B1(t+2)->c;  vmcnt(6); BAR; 16 MFMA (1,1); BAR
// Each MFMA cluster is pinned with sched_barrier(0) on both sides: MFMA
// intrinsics are register-only, so without these the LLVM scheduler migrates
// them across the asm waitcnt/barrier fences (rule #18) and collapses the
// 8-phase interleave back to a 2-barrier clump (observed: 724 TF == 2-barrier
// baseline, MfmaUtil 27.5%).
// ---------------------------------------------------------------------------
__device__ __forceinline__ void stage_half256(
    const unsigned short* __restrict__ g, int k0,
    unsigned short* lds, int wave, int lane) {
  const int gchunk = (lane & 7) ^ (lane >> 3);
#pragma unroll
  for (int j = 0; j < 2; ++j) {
    const int grp = wave * 2 + j;
    const unsigned short* gp =
        g + (size_t)(grp * 8 + (lane >> 3)) * CDIM + k0 + gchunk * 8;
    __builtin_amdgcn_global_load_lds(
        (const __attribute__((address_space(1))) unsigned int*)gp,
        (__attribute__((address_space(3))) unsigned int*)(lds + grp * 512),
        16, 0, 0);
  }
}

__device__ __forceinline__ void read_fragsA(
    const unsigned short* h, int roff, short8 fr[4][2], int l16, int quad) {
#pragma unroll
  for (int mf = 0; mf < 4; ++mf)
#pragma unroll
    for (int kh = 0; kh < 2; ++kh) {
      const int slot = (((kh << 2) | quad) ^ (l16 & 7)) * 8;
      fr[mf][kh] = *(const short8*)&h[(roff + mf * 16 + l16) * 64 + slot];
    }
}

__device__ __forceinline__ void read_fragsB(
    const unsigned short* h, int roff, short8 fr[2][2], int l16, int quad) {
#pragma unroll
  for (int nf = 0; nf < 2; ++nf)
#pragma unroll
    for (int kh = 0; kh < 2; ++kh) {
      const int slot = (((kh << 2) | quad) ^ (l16 & 7)) * 8;
      fr[nf][kh] = *(const short8*)&h[(roff + nf * 16 + l16) * 64 + slot];
    }
}

#define MFMA_PHASE(GM, GN, BB)                                              \
  do {                                                                      \
    SCHED_FENCE();                                                          \
    __builtin_amdgcn_s_setprio(1);                                          \
    _Pragma("unroll") for (int mf = 0; mf < 4; ++mf)                        \
    _Pragma("unroll") for (int nf = 0; nf < 2; ++nf)                        \
    _Pragma("unroll") for (int kh = 0; kh < 2; ++kh)                        \
        acc[GM][GN][mf][nf] =                                               \
            MFMA16(afr[mf][kh], BB[nf][kh], acc[GM][GN][mf][nf]);           \
    __builtin_amdgcn_s_setprio(0);                                          \
    SCHED_FENCE();                                                          \
  } while (0)

// Combined qkv (layout_x@Wqkv, 288 blocks) + kv (text_x@Wkv, 192 blocks):
// both K=768, equal-cost blocks, 480 total = 94%-balanced 2 rounds.
// Last 768-slice of each is written transposed into vTd[b][d][n].
__global__ __launch_bounds__(512, 2) void gemm_qkvkv(
    const unsigned short* __restrict__ A0g, const unsigned short* __restrict__ B0g,
    const float* __restrict__ bias0, unsigned short* __restrict__ Y0,
    unsigned short* __restrict__ vT0,
    const unsigned short* __restrict__ A1g, const unsigned short* __restrict__ B1g,
    const float* __restrict__ bias1, unsigned short* __restrict__ Y1,
    unsigned short* __restrict__ vT1) {
  __shared__ __align__(16) unsigned short lds[65536];  // 128 KiB
  int lin = blockIdx.x;
  const unsigned short *A, *Bt; const float* bias;
  unsigned short *Y, *vTd; int lastSlice, m0, c0;
  if (lin < 288) {            // qkv: 32 m-tiles x 9 c-tiles
    A = A0g; Bt = B0g; bias = bias0; Y = Y0; vTd = vT0; lastSlice = 2;
    const int xcd = lin & 7, j = lin >> 3;          // j in [0,36)
    m0 = (xcd * 4 + (j & 3)) * 256; c0 = (j >> 2) * 256;
  } else {                    // kv: 32 m-tiles x 6 c-tiles
    lin -= 288;
    A = A1g; Bt = B1g; bias = bias1; Y = Y1; vTd = vT1; lastSlice = 1;
    const int xcd = lin & 7, j = lin >> 3;          // j in [0,24)
    m0 = (xcd * 4 + (j & 3)) * 256; c0 = (j >> 2) * 256;
  }
  const int tid = threadIdx.x;
  const int wave = tid >> 6, lane = tid & 63;
  const int wy = wave >> 2, wx = wave & 3;          // 2 x 4 waves
  const int quad = lane >> 4, l16 = lane & 15;

  const unsigned short* Ah[2] = {A + (size_t)m0 * CDIM,
                                 A + (size_t)(m0 + 128) * CDIM};
  const unsigned short* Bh[2] = {Bt + (size_t)c0 * CDIM,
                                 Bt + (size_t)(c0 + 128) * CDIM};

  const f32x4 vzero = {0.f, 0.f, 0.f, 0.f};
  f32x4 acc[2][2][4][2];
#pragma unroll
  for (int gm = 0; gm < 2; ++gm)
#pragma unroll
    for (int gn = 0; gn < 2; ++gn)
#pragma unroll
      for (int mf = 0; mf < 4; ++mf)
#pragma unroll
        for (int nf = 0; nf < 2; ++nf) acc[gm][gn][mf][nf] = vzero;
  short8 afr[4][2], b0r[2][2], b1r[2][2];

  // Prologue: kt0 {A0,B0,B1,A1} + kt1 {A0,B0,B1}; wait kt0 landed (6 left).
  stage_half256(Ah[0], 0, lds + 0, wave, lane);
  stage_half256(Bh[0], 0, lds + 16384, wave, lane);
  stage_half256(Bh[1], 0, lds + 24576, wave, lane);
  stage_half256(Ah[1], 0, lds + 8192, wave, lane);
  stage_half256(Ah[0], 64, lds + 32768 + 0, wave, lane);
  stage_half256(Bh[0], 64, lds + 32768 + 16384, wave, lane);
  stage_half256(Bh[1], 64, lds + 32768 + 24576, wave, lane);
  WAIT_VM6();
  BAR(); FENCE();

  for (int t = 0; t < 12; ++t) {
    unsigned short* bufc = lds + (t & 1) * 32768;
    unsigned short* bufn = lds + ((t + 1) & 1) * 32768;
    // ---- phase 0: quadrant (0,0) ----
    read_fragsA(bufc + 0, wy * 64, afr, l16, quad);
    read_fragsB(bufc + 16384, wx * 32, b0r, l16, quad);
    if (t < 11) stage_half256(Ah[1], (t + 1) * 64, bufn + 8192, wave, lane);
    BAR(); WAIT_LGKM0();
    MFMA_PHASE(0, 0, b0r);
    BAR(); FENCE();
    // ---- phase 1: quadrant (0,1) ----
    read_fragsB(bufc + 24576, wx * 32, b1r, l16, quad);
    if (t < 10) stage_half256(Ah[0], (t + 2) * 64, bufc + 0, wave, lane);
    BAR(); WAIT_LGKM0();
    MFMA_PHASE(0, 1, b1r);
    BAR(); FENCE();
    // ---- phase 2: quadrant (1,0) ----
    read_fragsA(bufc + 8192, wy * 64, afr, l16, quad);
    if (t < 10) stage_half256(Bh[0], (t + 2) * 64, bufc + 16384, wave, lane);
    BAR(); WAIT_LGKM0();
    MFMA_PHASE(1, 0, b0r);
    BAR(); FENCE();
    // ---- phase 3: quadrant (1,1) + K-tile boundary ----
    if (t < 10) {
      stage_half256(Bh[1], (t + 2) * 64, bufc + 24576, wave, lane);
      WAIT_VM6();
    } else if (t == 10) {
      WAIT_VM0();
    }
    BAR(); WAIT_LGKM0();
    MFMA_PHASE(1, 1, b1r);
    BAR(); FENCE();
  }

  // Epilogue: slice-routed writes (last slice transposed to vTd[b][d][n]).
#pragma unroll
  for (int gm = 0; gm < 2; ++gm)
#pragma unroll
    for (int gn = 0; gn < 2; ++gn) {
      const int cb2 = c0 + gn * 128 + wx * 32;
      const int slice = cb2 / 768;
      const int rb = m0 + gm * 128 + wy * 64;
      if (slice == lastSlice) {
#pragma unroll
        for (int mf = 0; mf < 4; ++mf) {
          const int row0 = rb + mf * 16 + quad * 4;
          const int b = row0 >> 10, n0 = row0 & 1023;
#pragma unroll
          for (int nf = 0; nf < 2; ++nf) {
            const int gcol = cb2 + nf * 16 + l16;
            const int d = gcol - slice * 768;
            const float bv = bias[gcol];
            uint2 o;
            o.x = (unsigned)f2bf(acc[gm][gn][mf][nf][0] + bv) |
                  ((unsigned)f2bf(acc[gm][gn][mf][nf][1] + bv) << 16);
            o.y = (unsigned)f2bf(acc[gm][gn][mf][nf][2] + bv) |
                  ((unsigned)f2bf(acc[gm][gn][mf][nf][3] + bv) << 16);
            *(uint2*)&vTd[((size_t)b * CDIM + d) * MDIM + n0] = o;
          }
        }
      } else {
        const size_t sbase = (size_t)slice * ROWS * 768;
#pragma unroll
        for (int mf = 0; mf < 4; ++mf)
#pragma unroll
          for (int nf = 0; nf < 2; ++nf) {
            const int gcol = cb2 + nf * 16 + l16;
            const int lcol = gcol - slice * 768;
            const float bv = bias[gcol];
#pragma unroll
            for (int rg = 0; rg < 4; ++rg) {
              const int row = rb + mf * 16 + quad * 4 + rg;
              Y[sbase + (size_t)row * 768 + lcol] =
                  f2bf(acc[gm][gn][mf][nf][rg] + bv);
            }
          }
      }
    }
}

// ---------------------------------------------------------------------------
// cq / FFN projections on the 128x128 engine.
// ---------------------------------------------------------------------------
__global__ __launch_bounds__(256, 4) void gemm_proj(
    const unsigned short* __restrict__ A, const unsigned short* __restrict__ Bt,
    const float* __restrict__ bias, unsigned short* __restrict__ Y,
    unsigned short* __restrict__ vTd, int trans) {
  __shared__ __align__(16) unsigned short As[128 * 64];
  __shared__ __align__(16) unsigned short Bs[128 * 64];
  int m0, c0;
  swizzle_mc(blockIdx.y * gridDim.x + blockIdx.x, &m0, &c0);
  const int tid = threadIdx.x;
  const int wave = tid >> 6, lane = tid & 63;
  const f32x4 vzero = {0.f, 0.f, 0.f, 0.f};
  f32x4 acc[4][4];
#pragma unroll
  for (int mt = 0; mt < 4; ++mt)
#pragma unroll
    for (int nt = 0; nt < 4; ++nt) acc[mt][nt] = vzero;
  mfma_loop64(A + (size_t)m0 * CDIM, CDIM, Bt + (size_t)c0 * CDIM, CDIM, CDIM,
              As, Bs, acc, wave, lane);
  proj_epilogue(acc, bias, Y, vTd, c0, m0, (int)(gridDim.x / 6) - 1, trans,
                wave, lane);
}

__global__ __launch_bounds__(256, 4) void gemm_ffn(
    const unsigned short* __restrict__ A, const unsigned short* __restrict__ Bt,
    const float* __restrict__ bias, float* __restrict__ Y) {
  __shared__ __align__(16) unsigned short As[128 * 64];
  __shared__ __align__(16) unsigned short Bs[128 * 64];
  int m0, c0;
  swizzle_mc(blockIdx.y * gridDim.x + blockIdx.x, &m0, &c0);
  const int tid = threadIdx.x;
  const int wave = tid >> 6, lane = tid & 63;
  const int wx = wave & 1, wy = wave >> 1;
  const int quad = lane >> 4, l16 = lane & 15;
  const f32x4 vzero = {0.f, 0.f, 0.f, 0.f};
  f32x4 acc[4][4];
#pragma unroll
  for (int mt = 0; mt < 4; ++mt)
#pragma unroll
    for (int nt = 0; nt < 4; ++nt) acc[mt][nt] = vzero;
  mfma_loop64(A + (size_t)m0 * CDIM, CDIM, Bt + (size_t)c0 * CDIM, CDIM, CDIM,
              As, Bs, acc, wave, lane);
#pragma unroll
  for (int mt = 0; mt < 4; ++mt)
#pragma unroll
    for (int nt = 0; nt < 4; ++nt) {
      const int col = c0 + wx * 64 + nt * 16 + l16;
      const float bv = bias[col];
#pragma unroll
      for (int rg = 0; rg < 4; ++rg) {
        const int row = m0 + wy * 64 + mt * 16 + quad * 4 + rg;
        Y[(size_t)row * 768 + col] = acc[mt][nt][rg] + bv;
      }
    }
}

// ---------------------------------------------------------------------------
// Batched QK^T with fused exp + row-sum: S[b] = exp(scale*QK^T) (masked ->
// 1e-30f). Row sums stored as race-free partials per (cblock, wx):
// rsp[((cb*2+wx)*8 + b)*1024 + row]  (16 partials per row, no atomics,
// no zero-init needed). grid (8,8,BDIM).
// ---------------------------------------------------------------------------
__global__ __launch_bounds__(256, 4) void gemm_qk(
    const unsigned short* __restrict__ Qb, const unsigned short* __restrict__ Kb,
    const float* __restrict__ mask, unsigned short* __restrict__ S, float scale,
    float* __restrict__ rsp) {
  __shared__ __align__(16) unsigned short As[128 * 64];
  __shared__ __align__(16) unsigned short Bs[128 * 64];
  const int c0 = blockIdx.x * 128;
  const int m0 = blockIdx.y * 128;
  const int b = blockIdx.z;
  const int tid = threadIdx.x;
  const int wave = tid >> 6, lane = tid & 63;
  const int wx = wave & 1, wy = wave >> 1;
  const int quad = lane >> 4, l16 = lane & 15;

  const f32x4 vzero = {0.f, 0.f, 0.f, 0.f};
  f32x4 acc[4][4];
#pragma unroll
  for (int mt = 0; mt < 4; ++mt)
#pragma unroll
    for (int nt = 0; nt < 4; ++nt) acc[mt][nt] = vzero;

  mfma_loop64(Qb + ((size_t)b * MDIM + m0) * CDIM, CDIM,
              Kb + ((size_t)b * MDIM + c0) * CDIM, CDIM, CDIM,
              As, Bs, acc, wave, lane);

  const float* maskb = mask + b * MDIM;
  float mrow[4][4], rsum[4][4];
#pragma unroll
  for (int mt = 0; mt < 4; ++mt)
#pragma unroll
    for (int rg = 0; rg < 4; ++rg) {
      mrow[mt][rg] = maskb[m0 + wy * 64 + mt * 16 + quad * 4 + rg];
      rsum[mt][rg] = 0.f;
    }
  unsigned short* Sb = S + (size_t)b * MDIM * MDIM;
#pragma unroll
  for (int nt = 0; nt < 4; ++nt) {
    const int col = c0 + wx * 64 + nt * 16 + l16;
    const float mcol = maskb[col];
#pragma unroll
    for (int mt = 0; mt < 4; ++mt)
#pragma unroll
      for (int rg = 0; rg < 4; ++rg) {
        const int row = m0 + wy * 64 + mt * 16 + quad * 4 + rg;
        const float e = (mrow[mt][rg] * mcol != 0.f)
                            ? __expf(acc[mt][nt][rg] * scale)
                            : 1e-30f;
        Sb[(size_t)row * MDIM + col] = f2bf(e);
        rsum[mt][rg] += e;
      }
  }
  // reduce across the 16 lanes of each quad (they share rows)
  for (int off = 1; off < 16; off <<= 1) {
#pragma unroll
    for (int mt = 0; mt < 4; ++mt)
#pragma unroll
      for (int rg = 0; rg < 4; ++rg)
        rsum[mt][rg] += __shfl_xor(rsum[mt][rg], off, 64);
  }
  if (l16 == 0) {
    float* rs = rsp + ((((size_t)blockIdx.x * 2 + wx) * 8 + b) << 10) +
                m0 + wy * 64;
#pragma unroll
    for (int mt = 0; mt < 4; ++mt)
#pragma unroll
      for (int rg = 0; rg < 4; ++rg)
        rs[mt * 16 + quad * 4 + rg] = rsum[mt][rg];
  }
}

// ---------------------------------------------------------------------------
// O = (unnormalized P) @ V, normalized by 1/rowsum per row. rowsum = sum of
// 16 partials (lane l16 loads partial p=l16, 16-lane shuffle reduce).
// grid (6, 8, BDIM).
// ---------------------------------------------------------------------------
__global__ __launch_bounds__(256, 4) void attn_pv(
    const unsigned short* __restrict__ P, const unsigned short* __restrict__ vT,
    unsigned short* __restrict__ O, const float* __restrict__ rsp) {
  __shared__ __align__(16) unsigned short As[128 * 64];
  __shared__ __align__(16) unsigned short Bs[128 * 64];
  const int c0 = blockIdx.x * 128;
  const int m0 = blockIdx.y * 128;
  const int b = blockIdx.z;
  const int tid = threadIdx.x;
  const int wave = tid >> 6, lane = tid & 63;
  const int wx = wave & 1, wy = wave >> 1;
  const int quad = lane >> 4, l16 = lane & 15;

  const f32x4 vzero = {0.f, 0.f, 0.f, 0.f};
  f32x4 acc[4][4];
#pragma unroll
  for (int mt = 0; mt < 4; ++mt)
#pragma unroll
    for (int nt = 0; nt < 4; ++nt) acc[mt][nt] = vzero;

  mfma_loop64(P + ((size_t)b * MDIM + m0) * MDIM, MDIM,
              vT + ((size_t)b * CDIM + c0) * MDIM, MDIM, MDIM,
              As, Bs, acc, wave, lane);

  const float* rsb = rsp + (((size_t)l16 * 8 + b) << 10) + m0 + wy * 64;
  float inv[4][4];
#pragma unroll
  for (int mt = 0; mt < 4; ++mt)
#pragma unroll
    for (int rg = 0; rg < 4; ++rg) {
      float s = rsb[mt * 16 + quad * 4 + rg];
      for (int off = 1; off < 16; off <<= 1) s += __shfl_xor(s, off, 64);
      inv[mt][rg] = 1.f / s;
    }
#pragma unroll
  for (int mt = 0; mt < 4; ++mt)
#pragma unroll
    for (int nt = 0; nt < 4; ++nt)
#pragma unroll
      for (int rg = 0; rg < 4; ++rg) {
        const int row = m0 + wy * 64 + mt * 16 + quad * 4 + rg;
        const int col = c0 + wx * 64 + nt * 16 + l16;
        O[(size_t)(b * MDIM + row) * CDIM + col] =
            f2bf(acc[mt][nt][rg] * inv[mt][rg]);
      }
}

// ---------------------------------------------------------------------------
extern "C" void kernel_launch(void* const* d_in, const int* in_sizes, int n_in,
                              void* d_out, int out_size, void* d_ws, size_t ws_size,
                              hipStream_t stream) {
  const float* layout_x = (const float*)d_in[0];
  const float* text_x   = (const float*)d_in[1];
  const float* maskp    = (const float*)d_in[2];
  const float* Wqkv     = (const float*)d_in[3];
  const float* bqkv     = (const float*)d_in[4];
  const float* Wq       = (const float*)d_in[5];
  const float* bq       = (const float*)d_in[6];
  const float* Wkv      = (const float*)d_in[7];
  const float* bkv      = (const float*)d_in[8];
  const float* Wffn     = (const float*)d_in[9];
  const float* bffn     = (const float*)d_in[10];
  float* out = (float*)d_out;
  char* ws = (char*)d_ws;

  const float scale = 1.0f / sqrtf((float)CDIM);

  // ---- workspace (bytes), live total 87,949,312 ----
  unsigned short* xlb    = (unsigned short*)(ws);              // -> attn1/merge
  unsigned short* xtb    = (unsigned short*)(ws + 12582912);   // dead after proj -> rsp
  unsigned short* Wqkv_t = (unsigned short*)(ws + 25165824);
  unsigned short* Wq_t   = (unsigned short*)(ws + 28704768);
  unsigned short* Wkv_t  = (unsigned short*)(ws + 29884416);
  unsigned short* Wffn_t = (unsigned short*)(ws + 32243712);
  unsigned short* Qb     = (unsigned short*)(ws + 33423360);   // slice1=K contiguous
  unsigned short* Kb     = (unsigned short*)(ws + 46006272);
  unsigned short* vT     = (unsigned short*)(ws + 58589184);   // V^T
  unsigned short* S      = (unsigned short*)(ws + 71172096);   // 16.8 MB
  unsigned short* attn1  = xlb;
  unsigned short* cqb    = Qb;           // Qb dead after qk1
  // cross-attention K / V^T live in d_out (exactly 2 x 12,582,912 B);
  // ffn overwrites out only after pv2 consumed them.
  unsigned short* cK  = (unsigned short*)out;
  unsigned short* cVT = (unsigned short*)out + 6291456;
  // rowsum partials (512 KB) in the xtb region (dead after gemm_qkvkv).
  float* rsp = (float*)xtb;

  // 1) prologue: input converts + weight transposes
  prologue<<<10176, 256, 0, stream>>>(layout_x, text_x, xlb, xtb,
                                      Wqkv, Wq, Wkv, Wffn,
                                      Wqkv_t, Wq_t, Wkv_t, Wffn_t);
  // 2) combined 8-phase 256^2: {Q,K -> Qb,Kb; V -> vT^T} + {cK -> out; cV -> cVT^T}
  gemm_qkvkv<<<480, 512, 0, stream>>>(xlb, Wqkv_t, bqkv, Qb, vT,
                                      xtb, Wkv_t, bkv, cK, cVT);
  // 3) S = exp(scale*QK^T) masked; rowsum partials
  gemm_qk<<<dim3(8, 8, BDIM), 256, 0, stream>>>(Qb, Kb, maskp, S, scale, rsp);
  // 4) attn1 = bf16((S @ V) / rowsum)
  attn_pv<<<dim3(6, 8, BDIM), 256, 0, stream>>>(S, vT, attn1, rsp);
  // 5) cq = attn1@Wq+bq
  gemm_proj<<<dim3(6, 64), 256, 0, stream>>>(attn1, Wq_t, bq, cqb, vT, 0);
  // 6) S = exp(scale*cq cK^T) masked; rowsum partials
  gemm_qk<<<dim3(8, 8, BDIM), 256, 0, stream>>>(cqb, cK, maskp, S, scale, rsp);
  // 7) merge = bf16((S @ cV) / rowsum)
  attn_pv<<<dim3(6, 8, BDIM), 256, 0, stream>>>(S, cVT, attn1, rsp);
  // 8) out = merge @ Wffn + bffn (f32)
  gemm_ffn<<<dim3(6, 64), 256, 0, stream>>>(attn1, Wffn_t, bffn, out);
}

// Round 3
// 311.779 us; speedup vs baseline: 1.0128x; 1.0128x over previous
//
#include <hip/hip_runtime.h>
#include <math.h>

#define BDIM 8
#define MDIM 1024
#define CDIM 768
#define ROWS (BDIM * MDIM)   // 8192

typedef __attribute__((ext_vector_type(8))) short short8;   // 8 bf16
typedef __attribute__((ext_vector_type(8))) unsigned short ushort8;
typedef __attribute__((ext_vector_type(4))) float f32x4;

#define MFMA16(a, b, c) __builtin_amdgcn_mfma_f32_16x16x32_bf16((a), (b), (c), 0, 0, 0)

#define BAR() __builtin_amdgcn_s_barrier()
#define FENCE() asm volatile("" ::: "memory")
#define SCHED_FENCE() __builtin_amdgcn_sched_barrier(0)
#define WAIT_LGKM0() asm volatile("s_waitcnt lgkmcnt(0)" ::: "memory")
#define WAIT_VM6() asm volatile("s_waitcnt vmcnt(6)" ::: "memory")
#define WAIT_VM0() asm volatile("s_waitcnt vmcnt(0)" ::: "memory")

__device__ __forceinline__ unsigned short f2bf(float f) {
  unsigned u = __float_as_uint(f);
  return (unsigned short)((u + 0x7FFFu + ((u >> 16) & 1u)) >> 16);
}

// ---------------------------------------------------------------------------
// Prologue (one launch): input converts + weight transpose-converts.
// Flat grid of 10176 blocks x 256 threads:
//   [0,3072): convert layout_x; [3072,6144): convert text_x;
//   [6144,10176): transpose_w (168x24).
// ---------------------------------------------------------------------------
__global__ __launch_bounds__(256) void prologue(
    const float* __restrict__ xl, const float* __restrict__ xt,
    unsigned short* __restrict__ dxl, unsigned short* __restrict__ dxt,
    const float* __restrict__ W0, const float* __restrict__ W1,
    const float* __restrict__ W2, const float* __restrict__ W3,
    unsigned short* __restrict__ D0, unsigned short* __restrict__ D1,
    unsigned short* __restrict__ D2, unsigned short* __restrict__ D3) {
  const int bx = blockIdx.x;
  const int tid = threadIdx.x;
  if (bx < 6144) {
    const float* src = bx < 3072 ? xl : xt;
    unsigned short* dst = bx < 3072 ? dxl : dxt;
    const int i = ((bx < 3072 ? bx : bx - 3072) * 256 + tid) * 8;
    const float4 a = *(const float4*)(src + i);
    const float4 b = *(const float4*)(src + i + 4);
    ushort8 o;
    o[0] = f2bf(a.x); o[1] = f2bf(a.y); o[2] = f2bf(a.z); o[3] = f2bf(a.w);
    o[4] = f2bf(b.x); o[5] = f2bf(b.y); o[6] = f2bf(b.z); o[7] = f2bf(b.w);
    *(ushort8*)(dst + i) = o;
  } else {
    int x = bx - 6144;
    int bxx = x % 168;
    const int k0 = (x / 168) * 32;
    const float* W; unsigned short* D; int N;
    if (bxx < 72)       { W = W0; D = D0; N = 2304; }
    else if (bxx < 96)  { W = W1; D = D1; N = 768;  bxx -= 72; }
    else if (bxx < 144) { W = W2; D = D2; N = 1536; bxx -= 96; }
    else                { W = W3; D = D3; N = 768;  bxx -= 144; }
    __shared__ unsigned short t[32][33];
    const int tx = tid & 31, ty = tid >> 5;
    const int n0 = bxx * 32;
#pragma unroll
    for (int i = 0; i < 4; ++i)
      t[ty + i * 8][tx] = f2bf(W[(size_t)(k0 + ty + i * 8) * N + n0 + tx]);
    __syncthreads();
#pragma unroll
    for (int i = 0; i < 4; ++i)
      D[(size_t)(n0 + ty + i * 8) * CDIM + k0 + tx] = t[tx][ty + i * 8];
  }
}

// ---------------------------------------------------------------------------
// BK=64 MFMA engine (128x128 tile, 2-barrier structure) — kept for the
// attention-middle kernels and the small cq projection.
// ---------------------------------------------------------------------------
__device__ __forceinline__ void stage64(
    const unsigned short* __restrict__ g, int ld, int k0,
    unsigned short* lds, int wave, int lane) {
  const int gchunk = (lane & 7) ^ (lane >> 3);
#pragma unroll
  for (int j = 0; j < 4; ++j) {
    const int grp = wave * 4 + j;
    const unsigned short* gp =
        g + (size_t)(grp * 8 + (lane >> 3)) * ld + k0 + gchunk * 8;
    __builtin_amdgcn_global_load_lds(
        (const __attribute__((address_space(1))) unsigned int*)gp,
        (__attribute__((address_space(3))) unsigned int*)(lds + grp * 512),
        16, 0, 0);
  }
}

__device__ __forceinline__ void mfma_loop64(
    const unsigned short* __restrict__ A, int lda,
    const unsigned short* __restrict__ Bt, int ldb, int K,
    unsigned short* As, unsigned short* Bs, f32x4 acc[4][4],
    int wave, int lane) {
  const int wx = wave & 1, wy = wave >> 1;
  const int quad = lane >> 4, l16 = lane & 15;
  for (int k0 = 0; k0 < K; k0 += 64) {
    stage64(A, lda, k0, As, wave, lane);
    stage64(Bt, ldb, k0, Bs, wave, lane);
    __syncthreads();
#pragma unroll
    for (int h = 0; h < 2; ++h) {
      const int slot = ((((h << 2) | quad) ^ (l16 & 7))) * 8;
      short8 afr[4], bfr[4];
#pragma unroll
      for (int mt = 0; mt < 4; ++mt)
        afr[mt] = *(const short8*)&As[(wy * 64 + mt * 16 + l16) * 64 + slot];
#pragma unroll
      for (int nt = 0; nt < 4; ++nt)
        bfr[nt] = *(const short8*)&Bs[(wx * 64 + nt * 16 + l16) * 64 + slot];
#pragma unroll
      for (int mt = 0; mt < 4; ++mt)
#pragma unroll
        for (int nt = 0; nt < 4; ++nt)
          acc[mt][nt] = MFMA16(afr[mt], bfr[nt], acc[mt][nt]);
    }
    __syncthreads();
  }
}

// Projection epilogue for the 128x128 engine (slice-routed bf16 write).
__device__ __forceinline__ void proj_epilogue(
    f32x4 acc[4][4], const float* __restrict__ bias,
    unsigned short* __restrict__ Y, unsigned short* __restrict__ vTd,
    int c0, int m0, int lastSlice, int trans, int wave, int lane) {
  const int wx = wave & 1, wy = wave >> 1;
  const int quad = lane >> 4, l16 = lane & 15;
  const int slice = c0 / 768;
  if (trans && slice == lastSlice) {
#pragma unroll
    for (int mt = 0; mt < 4; ++mt) {
      const int row0 = m0 + wy * 64 + mt * 16 + quad * 4;
      const int b = row0 >> 10, n0 = row0 & 1023;
#pragma unroll
      for (int nt = 0; nt < 4; ++nt) {
        const int gcol = c0 + wx * 64 + nt * 16 + l16;
        const int d = gcol - slice * 768;
        const float bv = bias[gcol];
        uint2 o;
        o.x = (unsigned)f2bf(acc[mt][nt][0] + bv) |
              ((unsigned)f2bf(acc[mt][nt][1] + bv) << 16);
        o.y = (unsigned)f2bf(acc[mt][nt][2] + bv) |
              ((unsigned)f2bf(acc[mt][nt][3] + bv) << 16);
        *(uint2*)&vTd[((size_t)b * CDIM + d) * MDIM + n0] = o;
      }
    }
  } else {
    const size_t sbase = (size_t)slice * ROWS * 768;
#pragma unroll
    for (int mt = 0; mt < 4; ++mt)
#pragma unroll
      for (int nt = 0; nt < 4; ++nt) {
        const int gcol = c0 + wx * 64 + nt * 16 + l16;
        const int lcol = gcol - slice * 768;
        const float bv = bias[gcol];
#pragma unroll
        for (int rg = 0; rg < 4; ++rg) {
          const int row = m0 + wy * 64 + mt * 16 + quad * 4 + rg;
          Y[sbase + (size_t)row * 768 + lcol] = f2bf(acc[mt][nt][rg] + bv);
        }
      }
  }
}

// XCD-swizzled block mapping for (gx, 64) 128x128 grids.
__device__ __forceinline__ void swizzle_mc(int lin, int* m0, int* c0) {
  const int xcd = lin & 7, j = lin >> 3;
  *m0 = (xcd * 8 + (j & 7)) * 128;
  *c0 = (j >> 3) * 128;
}

// ---------------------------------------------------------------------------
// 256x256 engine, 4 phases per K-tile, ONE barrier per phase.
// 512 threads = 8 waves (2M x 4N); per-wave output 128x64; BK=64; 12 K-tiles
// (K=768). LDS 128 KiB: 2 dbuf x {A0,A1,B0,B1} halves of [128][64] bf16,
// chunk-XOR swizzled.
//
// Phase shape: [reads(p); stage(p); BAR; lgkm0; MFMA(p)] — no post-MFMA
// barrier. A wave that clears its MFMA immediately issues the next phase's
// ds_reads/stage while sibling waves are still in MFMA, mixing the LDS-read
// window with the MFMA window across waves (the 2-barrier version strictly
// serialized them CU-wide: measured MfmaUtil 27.5%).
//
// Schedule per K-tile t (bufc=t&1, bufn=t+1&1):
//   p0: read A0,B0(t);  stage A1(t+1)->bufn;            BAR lgkm0 MFMA(0,0)
//   p1: read B1(t);                                     BAR lgkm0 MFMA(0,1)
//   p2: read A1(t);     stage A0(t+2)->bufc;            BAR lgkm0 MFMA(1,0)
//   p3:                 stage B0,B1(t+2)->bufc; vm(6);  BAR       MFMA(1,1)
//
// Clobber safety (single-barrier rule: a stage targeting half H must issue
// >= 2 barriers after H's last read-ISSUE; the reader's own lgkmcnt(0) sits
// before the intervening barrier, so its registers are filled first):
//   A1(t+1)@p0(t): slot last read p2(t-1) -> BAR(p2),BAR(p3) intervene  OK
//   A0(t+2)@p2(t): slot last read p0(t)   -> BAR(p0),BAR(p1)            OK
//   B0(t+2)@p3(t): slot last read p0(t)   -> 3 barriers                 OK
//   B1(t+2)@p3(t): slot last read p1(t)   -> BAR(p1),BAR(p2)            OK
// vmcnt ledger (2 loads/thread per half, issue order per K-tile:
// A1(t+1)^2, A0(t+2)^2, B0(t+2)^2, B1(t+2)^2): vmcnt(6) at p3 leaves only
// the t+2 halves in flight => all t+1 halves landed before their reads.
// ---------------------------------------------------------------------------
__device__ __forceinline__ void stage_half256(
    const unsigned short* __restrict__ g, int k0,
    unsigned short* lds, int wave, int lane) {
  const int gchunk = (lane & 7) ^ (lane >> 3);
#pragma unroll
  for (int j = 0; j < 2; ++j) {
    const int grp = wave * 2 + j;
    const unsigned short* gp =
        g + (size_t)(grp * 8 + (lane >> 3)) * CDIM + k0 + gchunk * 8;
    __builtin_amdgcn_global_load_lds(
        (const __attribute__((address_space(1))) unsigned int*)gp,
        (__attribute__((address_space(3))) unsigned int*)(lds + grp * 512),
        16, 0, 0);
  }
}

__device__ __forceinline__ void read_fragsA(
    const unsigned short* h, int roff, short8 fr[4][2], int l16, int quad) {
#pragma unroll
  for (int mf = 0; mf < 4; ++mf)
#pragma unroll
    for (int kh = 0; kh < 2; ++kh) {
      const int slot = (((kh << 2) | quad) ^ (l16 & 7)) * 8;
      fr[mf][kh] = *(const short8*)&h[(roff + mf * 16 + l16) * 64 + slot];
    }
}

__device__ __forceinline__ void read_fragsB(
    const unsigned short* h, int roff, short8 fr[2][2], int l16, int quad) {
#pragma unroll
  for (int nf = 0; nf < 2; ++nf)
#pragma unroll
    for (int kh = 0; kh < 2; ++kh) {
      const int slot = (((kh << 2) | quad) ^ (l16 & 7)) * 8;
      fr[nf][kh] = *(const short8*)&h[(roff + nf * 16 + l16) * 64 + slot];
    }
}

#define MFMA_PHASE(GM, GN, BB)                                              \
  do {                                                                      \
    SCHED_FENCE();                                                          \
    __builtin_amdgcn_s_setprio(1);                                          \
    _Pragma("unroll") for (int mf = 0; mf < 4; ++mf)                        \
    _Pragma("unroll") for (int nf = 0; nf < 2; ++nf)                        \
    _Pragma("unroll") for (int kh = 0; kh < 2; ++kh)                        \
        acc[GM][GN][mf][nf] =                                               \
            MFMA16(afr[mf][kh], BB[nf][kh], acc[GM][GN][mf][nf]);           \
    __builtin_amdgcn_s_setprio(0);                                          \
    SCHED_FENCE();                                                          \
  } while (0)

// Combined qkv (layout_x@Wqkv, 288 blocks) + kv (text_x@Wkv, 192 blocks):
// both K=768, equal-cost blocks, 480 total = 94%-balanced 2 rounds.
// Last 768-slice of each is written transposed into vTd[b][d][n].
__global__ __launch_bounds__(512, 2) void gemm_qkvkv(
    const unsigned short* __restrict__ A0g, const unsigned short* __restrict__ B0g,
    const float* __restrict__ bias0, unsigned short* __restrict__ Y0,
    unsigned short* __restrict__ vT0,
    const unsigned short* __restrict__ A1g, const unsigned short* __restrict__ B1g,
    const float* __restrict__ bias1, unsigned short* __restrict__ Y1,
    unsigned short* __restrict__ vT1) {
  __shared__ __align__(16) unsigned short lds[65536];  // 128 KiB
  int lin = blockIdx.x;
  const unsigned short *A, *Bt; const float* bias;
  unsigned short *Y, *vTd; int lastSlice, m0, c0;
  if (lin < 288) {            // qkv: 32 m-tiles x 9 c-tiles
    A = A0g; Bt = B0g; bias = bias0; Y = Y0; vTd = vT0; lastSlice = 2;
    const int xcd = lin & 7, j = lin >> 3;          // j in [0,36)
    m0 = (xcd * 4 + (j & 3)) * 256; c0 = (j >> 2) * 256;
  } else {                    // kv: 32 m-tiles x 6 c-tiles
    lin -= 288;
    A = A1g; Bt = B1g; bias = bias1; Y = Y1; vTd = vT1; lastSlice = 1;
    const int xcd = lin & 7, j = lin >> 3;          // j in [0,24)
    m0 = (xcd * 4 + (j & 3)) * 256; c0 = (j >> 2) * 256;
  }
  const int tid = threadIdx.x;
  const int wave = tid >> 6, lane = tid & 63;
  const int wy = wave >> 2, wx = wave & 3;          // 2 x 4 waves
  const int quad = lane >> 4, l16 = lane & 15;

  const unsigned short* Ah[2] = {A + (size_t)m0 * CDIM,
                                 A + (size_t)(m0 + 128) * CDIM};
  const unsigned short* Bh[2] = {Bt + (size_t)c0 * CDIM,
                                 Bt + (size_t)(c0 + 128) * CDIM};

  const f32x4 vzero = {0.f, 0.f, 0.f, 0.f};
  f32x4 acc[2][2][4][2];
#pragma unroll
  for (int gm = 0; gm < 2; ++gm)
#pragma unroll
    for (int gn = 0; gn < 2; ++gn)
#pragma unroll
      for (int mf = 0; mf < 4; ++mf)
#pragma unroll
        for (int nf = 0; nf < 2; ++nf) acc[gm][gn][mf][nf] = vzero;
  short8 afr[4][2], b0r[2][2], b1r[2][2];

  // Prologue staging: kt0 {A0,B0,B1,A1} + kt1 {A0,B0,B1} (A1(1) is staged at
  // p0 of t=0). Wait kt0 landed (6 of kt1 left in flight).
  stage_half256(Ah[0], 0, lds + 0, wave, lane);
  stage_half256(Bh[0], 0, lds + 16384, wave, lane);
  stage_half256(Bh[1], 0, lds + 24576, wave, lane);
  stage_half256(Ah[1], 0, lds + 8192, wave, lane);
  stage_half256(Ah[0], 64, lds + 32768 + 0, wave, lane);
  stage_half256(Bh[0], 64, lds + 32768 + 16384, wave, lane);
  stage_half256(Bh[1], 64, lds + 32768 + 24576, wave, lane);
  WAIT_VM6();
  BAR(); FENCE();

  for (int t = 0; t < 12; ++t) {
    unsigned short* bufc = lds + (t & 1) * 32768;
    unsigned short* bufn = lds + ((t + 1) & 1) * 32768;
    // ---- phase 0: quadrant (0,0) ----
    read_fragsA(bufc + 0, wy * 64, afr, l16, quad);
    read_fragsB(bufc + 16384, wx * 32, b0r, l16, quad);
    if (t < 11) stage_half256(Ah[1], (t + 1) * 64, bufn + 8192, wave, lane);
    BAR(); WAIT_LGKM0();
    MFMA_PHASE(0, 0, b0r);
    // ---- phase 1: quadrant (0,1) ----
    read_fragsB(bufc + 24576, wx * 32, b1r, l16, quad);
    BAR(); WAIT_LGKM0();
    MFMA_PHASE(0, 1, b1r);
    // ---- phase 2: quadrant (1,0) ----
    read_fragsA(bufc + 8192, wy * 64, afr, l16, quad);
    if (t < 10) stage_half256(Ah[0], (t + 2) * 64, bufc + 0, wave, lane);
    BAR(); WAIT_LGKM0();
    MFMA_PHASE(1, 0, b0r);
    // ---- phase 3: quadrant (1,1) + K-tile boundary ----
    if (t < 10) {
      stage_half256(Bh[0], (t + 2) * 64, bufc + 16384, wave, lane);
      stage_half256(Bh[1], (t + 2) * 64, bufc + 24576, wave, lane);
      WAIT_VM6();
    } else if (t == 10) {
      WAIT_VM0();
    }
    BAR(); FENCE();
    MFMA_PHASE(1, 1, b1r);
  }

  // Epilogue: slice-routed writes (last slice transposed to vTd[b][d][n]).
#pragma unroll
  for (int gm = 0; gm < 2; ++gm)
#pragma unroll
    for (int gn = 0; gn < 2; ++gn) {
      const int cb2 = c0 + gn * 128 + wx * 32;
      const int slice = cb2 / 768;
      const int rb = m0 + gm * 128 + wy * 64;
      if (slice == lastSlice) {
#pragma unroll
        for (int mf = 0; mf < 4; ++mf) {
          const int row0 = rb + mf * 16 + quad * 4;
          const int b = row0 >> 10, n0 = row0 & 1023;
#pragma unroll
          for (int nf = 0; nf < 2; ++nf) {
            const int gcol = cb2 + nf * 16 + l16;
            const int d = gcol - slice * 768;
            const float bv = bias[gcol];
            uint2 o;
            o.x = (unsigned)f2bf(acc[gm][gn][mf][nf][0] + bv) |
                  ((unsigned)f2bf(acc[gm][gn][mf][nf][1] + bv) << 16);
            o.y = (unsigned)f2bf(acc[gm][gn][mf][nf][2] + bv) |
                  ((unsigned)f2bf(acc[gm][gn][mf][nf][3] + bv) << 16);
            *(uint2*)&vTd[((size_t)b * CDIM + d) * MDIM + n0] = o;
          }
        }
      } else {
        const size_t sbase = (size_t)slice * ROWS * 768;
#pragma unroll
        for (int mf = 0; mf < 4; ++mf)
#pragma unroll
          for (int nf = 0; nf < 2; ++nf) {
            const int gcol = cb2 + nf * 16 + l16;
            const int lcol = gcol - slice * 768;
            const float bv = bias[gcol];
#pragma unroll
            for (int rg = 0; rg < 4; ++rg) {
              const int row = rb + mf * 16 + quad * 4 + rg;
              Y[sbase + (size_t)row * 768 + lcol] =
                  f2bf(acc[gm][gn][mf][nf][rg] + bv);
            }
          }
      }
    }
}

// ---------------------------------------------------------------------------
// cq / FFN projections on the 128x128 engine.
// ---------------------------------------------------------------------------
__global__ __launch_bounds__(256, 4) void gemm_proj(
    const unsigned short* __restrict__ A, const unsigned short* __restrict__ Bt,
    const float* __restrict__ bias, unsigned short* __restrict__ Y,
    unsigned short* __restrict__ vTd, int trans) {
  __shared__ __align__(16) unsigned short As[128 * 64];
  __shared__ __align__(16) unsigned short Bs[128 * 64];
  int m0, c0;
  swizzle_mc(blockIdx.y * gridDim.x + blockIdx.x, &m0, &c0);
  const int tid = threadIdx.x;
  const int wave = tid >> 6, lane = tid & 63;
  const f32x4 vzero = {0.f, 0.f, 0.f, 0.f};
  f32x4 acc[4][4];
#pragma unroll
  for (int mt = 0; mt < 4; ++mt)
#pragma unroll
    for (int nt = 0; nt < 4; ++nt) acc[mt][nt] = vzero;
  mfma_loop64(A + (size_t)m0 * CDIM, CDIM, Bt + (size_t)c0 * CDIM, CDIM, CDIM,
              As, Bs, acc, wave, lane);
  proj_epilogue(acc, bias, Y, vTd, c0, m0, (int)(gridDim.x / 6) - 1, trans,
                wave, lane);
}

__global__ __launch_bounds__(256, 4) void gemm_ffn(
    const unsigned short* __restrict__ A, const unsigned short* __restrict__ Bt,
    const float* __restrict__ bias, float* __restrict__ Y) {
  __shared__ __align__(16) unsigned short As[128 * 64];
  __shared__ __align__(16) unsigned short Bs[128 * 64];
  int m0, c0;
  swizzle_mc(blockIdx.y * gridDim.x + blockIdx.x, &m0, &c0);
  const int tid = threadIdx.x;
  const int wave = tid >> 6, lane = tid & 63;
  const int wx = wave & 1, wy = wave >> 1;
  const int quad = lane >> 4, l16 = lane & 15;
  const f32x4 vzero = {0.f, 0.f, 0.f, 0.f};
  f32x4 acc[4][4];
#pragma unroll
  for (int mt = 0; mt < 4; ++mt)
#pragma unroll
    for (int nt = 0; nt < 4; ++nt) acc[mt][nt] = vzero;
  mfma_loop64(A + (size_t)m0 * CDIM, CDIM, Bt + (size_t)c0 * CDIM, CDIM, CDIM,
              As, Bs, acc, wave, lane);
#pragma unroll
  for (int mt = 0; mt < 4; ++mt)
#pragma unroll
    for (int nt = 0; nt < 4; ++nt) {
      const int col = c0 + wx * 64 + nt * 16 + l16;
      const float bv = bias[col];
#pragma unroll
      for (int rg = 0; rg < 4; ++rg) {
        const int row = m0 + wy * 64 + mt * 16 + quad * 4 + rg;
        Y[(size_t)row * 768 + col] = acc[mt][nt][rg] + bv;
      }
    }
}

// ---------------------------------------------------------------------------
// Batched QK^T with fused exp + row-sum: S[b] = exp(scale*QK^T) (masked ->
// 1e-30f). Row sums stored as race-free partials per (cblock, wx):
// rsp[((cb*2+wx)*8 + b)*1024 + row]  (16 partials per row, no atomics,
// no zero-init needed). grid (8,8,BDIM).
// ---------------------------------------------------------------------------
__global__ __launch_bounds__(256, 4) void gemm_qk(
    const unsigned short* __restrict__ Qb, const unsigned short* __restrict__ Kb,
    const float* __restrict__ mask, unsigned short* __restrict__ S, float scale,
    float* __restrict__ rsp) {
  __shared__ __align__(16) unsigned short As[128 * 64];
  __shared__ __align__(16) unsigned short Bs[128 * 64];
  const int c0 = blockIdx.x * 128;
  const int m0 = blockIdx.y * 128;
  const int b = blockIdx.z;
  const int tid = threadIdx.x;
  const int wave = tid >> 6, lane = tid & 63;
  const int wx = wave & 1, wy = wave >> 1;
  const int quad = lane >> 4, l16 = lane & 15;

  const f32x4 vzero = {0.f, 0.f, 0.f, 0.f};
  f32x4 acc[4][4];
#pragma unroll
  for (int mt = 0; mt < 4; ++mt)
#pragma unroll
    for (int nt = 0; nt < 4; ++nt) acc[mt][nt] = vzero;

  mfma_loop64(Qb + ((size_t)b * MDIM + m0) * CDIM, CDIM,
              Kb + ((size_t)b * MDIM + c0) * CDIM, CDIM, CDIM,
              As, Bs, acc, wave, lane);

  const float* maskb = mask + b * MDIM;
  float mrow[4][4], rsum[4][4];
#pragma unroll
  for (int mt = 0; mt < 4; ++mt)
#pragma unroll
    for (int rg = 0; rg < 4; ++rg) {
      mrow[mt][rg] = maskb[m0 + wy * 64 + mt * 16 + quad * 4 + rg];
      rsum[mt][rg] = 0.f;
    }
  unsigned short* Sb = S + (size_t)b * MDIM * MDIM;
#pragma unroll
  for (int nt = 0; nt < 4; ++nt) {
    const int col = c0 + wx * 64 + nt * 16 + l16;
    const float mcol = maskb[col];
#pragma unroll
    for (int mt = 0; mt < 4; ++mt)
#pragma unroll
      for (int rg = 0; rg < 4; ++rg) {
        const int row = m0 + wy * 64 + mt * 16 + quad * 4 + rg;
        const float e = (mrow[mt][rg] * mcol != 0.f)
                            ? __expf(acc[mt][nt][rg] * scale)
                            : 1e-30f;
        Sb[(size_t)row * MDIM + col] = f2bf(e);
        rsum[mt][rg] += e;
      }
  }
  // reduce across the 16 lanes of each quad (they share rows)
  for (int off = 1; off < 16; off <<= 1) {
#pragma unroll
    for (int mt = 0; mt < 4; ++mt)
#pragma unroll
      for (int rg = 0; rg < 4; ++rg)
        rsum[mt][rg] += __shfl_xor(rsum[mt][rg], off, 64);
  }
  if (l16 == 0) {
    float* rs = rsp + ((((size_t)blockIdx.x * 2 + wx) * 8 + b) << 10) +
                m0 + wy * 64;
#pragma unroll
    for (int mt = 0; mt < 4; ++mt)
#pragma unroll
      for (int rg = 0; rg < 4; ++rg)
        rs[mt * 16 + quad * 4 + rg] = rsum[mt][rg];
  }
}

// ---------------------------------------------------------------------------
// O = (unnormalized P) @ V, normalized by 1/rowsum per row. rowsum = sum of
// 16 partials (lane l16 loads partial p=l16, 16-lane shuffle reduce).
// grid (6, 8, BDIM).
// ---------------------------------------------------------------------------
__global__ __launch_bounds__(256, 4) void attn_pv(
    const unsigned short* __restrict__ P, const unsigned short* __restrict__ vT,
    unsigned short* __restrict__ O, const float* __restrict__ rsp) {
  __shared__ __align__(16) unsigned short As[128 * 64];
  __shared__ __align__(16) unsigned short Bs[128 * 64];
  const int c0 = blockIdx.x * 128;
  const int m0 = blockIdx.y * 128;
  const int b = blockIdx.z;
  const int tid = threadIdx.x;
  const int wave = tid >> 6, lane = tid & 63;
  const int wx = wave & 1, wy = wave >> 1;
  const int quad = lane >> 4, l16 = lane & 15;

  const f32x4 vzero = {0.f, 0.f, 0.f, 0.f};
  f32x4 acc[4][4];
#pragma unroll
  for (int mt = 0; mt < 4; ++mt)
#pragma unroll
    for (int nt = 0; nt < 4; ++nt) acc[mt][nt] = vzero;

  mfma_loop64(P + ((size_t)b * MDIM + m0) * MDIM, MDIM,
              vT + ((size_t)b * CDIM + c0) * MDIM, MDIM, MDIM,
              As, Bs, acc, wave, lane);

  const float* rsb = rsp + (((size_t)l16 * 8 + b) << 10) + m0 + wy * 64;
  float inv[4][4];
#pragma unroll
  for (int mt = 0; mt < 4; ++mt)
#pragma unroll
    for (int rg = 0; rg < 4; ++rg) {
      float s = rsb[mt * 16 + quad * 4 + rg];
      for (int off = 1; off < 16; off <<= 1) s += __shfl_xor(s, off, 64);
      inv[mt][rg] = 1.f / s;
    }
#pragma unroll
  for (int mt = 0; mt < 4; ++mt)
#pragma unroll
    for (int nt = 0; nt < 4; ++nt)
#pragma unroll
      for (int rg = 0; rg < 4; ++rg) {
        const int row = m0 + wy * 64 + mt * 16 + quad * 4 + rg;
        const int col = c0 + wx * 64 + nt * 16 + l16;
        O[(size_t)(b * MDIM + row) * CDIM + col] =
            f2bf(acc[mt][nt][rg] * inv[mt][rg]);
      }
}

// ---------------------------------------------------------------------------
extern "C" void kernel_launch(void* const* d_in, const int* in_sizes, int n_in,
                              void* d_out, int out_size, void* d_ws, size_t ws_size,
                              hipStream_t stream) {
  const float* layout_x = (const float*)d_in[0];
  const float* text_x   = (const float*)d_in[1];
  const float* maskp    = (const float*)d_in[2];
  const float* Wqkv     = (const float*)d_in[3];
  const float* bqkv     = (const float*)d_in[4];
  const float* Wq       = (const float*)d_in[5];
  const float* bq       = (const float*)d_in[6];
  const float* Wkv      = (const float*)d_in[7];
  const float* bkv      = (const float*)d_in[8];
  const float* Wffn     = (const float*)d_in[9];
  const float* bffn     = (const float*)d_in[10];
  float* out = (float*)d_out;
  char* ws = (char*)d_ws;

  const float scale = 1.0f / sqrtf((float)CDIM);

  // ---- workspace (bytes), live total 87,949,312 ----
  unsigned short* xlb    = (unsigned short*)(ws);              // -> attn1/merge
  unsigned short* xtb    = (unsigned short*)(ws + 12582912);   // dead after proj -> rsp
  unsigned short* Wqkv_t = (unsigned short*)(ws + 25165824);
  unsigned short* Wq_t   = (unsigned short*)(ws + 28704768);
  unsigned short* Wkv_t  = (unsigned short*)(ws + 29884416);
  unsigned short* Wffn_t = (unsigned short*)(ws + 32243712);
  unsigned short* Qb     = (unsigned short*)(ws + 33423360);   // slice1=K contiguous
  unsigned short* Kb     = (unsigned short*)(ws + 46006272);
  unsigned short* vT     = (unsigned short*)(ws + 58589184);   // V^T
  unsigned short* S      = (unsigned short*)(ws + 71172096);   // 16.8 MB
  unsigned short* attn1  = xlb;
  unsigned short* cqb    = Qb;           // Qb dead after qk1
  // cross-attention K / V^T live in d_out (exactly 2 x 12,582,912 B);
  // ffn overwrites out only after pv2 consumed them.
  unsigned short* cK  = (unsigned short*)out;
  unsigned short* cVT = (unsigned short*)out + 6291456;
  // rowsum partials (512 KB) in the xtb region (dead after gemm_qkvkv).
  float* rsp = (float*)xtb;

  // 1) prologue: input converts + weight transposes
  prologue<<<10176, 256, 0, stream>>>(layout_x, text_x, xlb, xtb,
                                      Wqkv, Wq, Wkv, Wffn,
                                      Wqkv_t, Wq_t, Wkv_t, Wffn_t);
  // 2) combined 256^2 engine: {Q,K -> Qb,Kb; V -> vT^T} + {cK -> out; cV -> cVT^T}
  gemm_qkvkv<<<480, 512, 0, stream>>>(xlb, Wqkv_t, bqkv, Qb, vT,
                                      xtb, Wkv_t, bkv, cK, cVT);
  // 3) S = exp(scale*QK^T) masked; rowsum partials
  gemm_qk<<<dim3(8, 8, BDIM), 256, 0, stream>>>(Qb, Kb, maskp, S, scale, rsp);
  // 4) attn1 = bf16((S @ V) / rowsum)
  attn_pv<<<dim3(6, 8, BDIM), 256, 0, stream>>>(S, vT, attn1, rsp);
  // 5) cq = attn1@Wq+bq
  gemm_proj<<<dim3(6, 64), 256, 0, stream>>>(attn1, Wq_t, bq, cqb, vT, 0);
  // 6) S = exp(scale*cq cK^T) masked; rowsum partials
  gemm_qk<<<dim3(8, 8, BDIM), 256, 0, stream>>>(cqb, cK, maskp, S, scale, rsp);
  // 7) merge = bf16((S @ cV) / rowsum)
  attn_pv<<<dim3(6, 8, BDIM), 256, 0, stream>>>(S, cVT, attn1, rsp);
  // 8) out = merge @ Wffn + bffn (f32)
  gemm_ffn<<<dim3(6, 64), 256, 0, stream>>>(attn1, Wffn_t, bffn, out);
}

// Round 4
// 311.683 us; speedup vs baseline: 1.0131x; 1.0003x over previous
//
#include <hip/hip_runtime.h>
#include <math.h>

#define BDIM 8
#define MDIM 1024
#define CDIM 768
#define ROWS (BDIM * MDIM)   // 8192

typedef __attribute__((ext_vector_type(8))) short short8;   // 8 bf16
typedef __attribute__((ext_vector_type(8))) unsigned short ushort8;
typedef __attribute__((ext_vector_type(4))) float f32x4;

#define MFMA16(a, b, c) __builtin_amdgcn_mfma_f32_16x16x32_bf16((a), (b), (c), 0, 0, 0)

#define BAR() __builtin_amdgcn_s_barrier()
#define FENCE() asm volatile("" ::: "memory")
#define SCHED_FENCE() __builtin_amdgcn_sched_barrier(0)
#define WAIT_LGKM0() asm volatile("s_waitcnt lgkmcnt(0)" ::: "memory")
#define WAIT_LGKM4() asm volatile("s_waitcnt lgkmcnt(4)" ::: "memory")
#define WAIT_LGKM8() asm volatile("s_waitcnt lgkmcnt(8)" ::: "memory")
#define WAIT_VM8() asm volatile("s_waitcnt vmcnt(8)" ::: "memory")
#define WAIT_VM6() asm volatile("s_waitcnt vmcnt(6)" ::: "memory")
#define WAIT_VM4() asm volatile("s_waitcnt vmcnt(4)" ::: "memory")
#define WAIT_VM2() asm volatile("s_waitcnt vmcnt(2)" ::: "memory")
#define WAIT_VM0() asm volatile("s_waitcnt vmcnt(0)" ::: "memory")

__device__ __forceinline__ unsigned short f2bf(float f) {
  unsigned u = __float_as_uint(f);
  return (unsigned short)((u + 0x7FFFu + ((u >> 16) & 1u)) >> 16);
}

// ---------------------------------------------------------------------------
// Prologue (one launch): input converts + weight transpose-converts.
// Flat grid of 10176 blocks x 256 threads:
//   [0,3072): convert layout_x; [3072,6144): convert text_x;
//   [6144,10176): transpose_w (168x24).
// ---------------------------------------------------------------------------
__global__ __launch_bounds__(256) void prologue(
    const float* __restrict__ xl, const float* __restrict__ xt,
    unsigned short* __restrict__ dxl, unsigned short* __restrict__ dxt,
    const float* __restrict__ W0, const float* __restrict__ W1,
    const float* __restrict__ W2, const float* __restrict__ W3,
    unsigned short* __restrict__ D0, unsigned short* __restrict__ D1,
    unsigned short* __restrict__ D2, unsigned short* __restrict__ D3) {
  const int bx = blockIdx.x;
  const int tid = threadIdx.x;
  if (bx < 6144) {
    const float* src = bx < 3072 ? xl : xt;
    unsigned short* dst = bx < 3072 ? dxl : dxt;
    const int i = ((bx < 3072 ? bx : bx - 3072) * 256 + tid) * 8;
    const float4 a = *(const float4*)(src + i);
    const float4 b = *(const float4*)(src + i + 4);
    ushort8 o;
    o[0] = f2bf(a.x); o[1] = f2bf(a.y); o[2] = f2bf(a.z); o[3] = f2bf(a.w);
    o[4] = f2bf(b.x); o[5] = f2bf(b.y); o[6] = f2bf(b.z); o[7] = f2bf(b.w);
    *(ushort8*)(dst + i) = o;
  } else {
    int x = bx - 6144;
    int bxx = x % 168;
    const int k0 = (x / 168) * 32;
    const float* W; unsigned short* D; int N;
    if (bxx < 72)       { W = W0; D = D0; N = 2304; }
    else if (bxx < 96)  { W = W1; D = D1; N = 768;  bxx -= 72; }
    else if (bxx < 144) { W = W2; D = D2; N = 1536; bxx -= 96; }
    else                { W = W3; D = D3; N = 768;  bxx -= 144; }
    __shared__ unsigned short t[32][33];
    const int tx = tid & 31, ty = tid >> 5;
    const int n0 = bxx * 32;
#pragma unroll
    for (int i = 0; i < 4; ++i)
      t[ty + i * 8][tx] = f2bf(W[(size_t)(k0 + ty + i * 8) * N + n0 + tx]);
    __syncthreads();
#pragma unroll
    for (int i = 0; i < 4; ++i)
      D[(size_t)(n0 + ty + i * 8) * CDIM + k0 + tx] = t[tx][ty + i * 8];
  }
}

// ---------------------------------------------------------------------------
// BK=64 MFMA engine (128x128 tile, 2-barrier structure) — kept for the
// attention-middle kernels and the small cq projection.
// ---------------------------------------------------------------------------
__device__ __forceinline__ void stage64(
    const unsigned short* __restrict__ g, int ld, int k0,
    unsigned short* lds, int wave, int lane) {
  const int gchunk = (lane & 7) ^ (lane >> 3);
#pragma unroll
  for (int j = 0; j < 4; ++j) {
    const int grp = wave * 4 + j;
    const unsigned short* gp =
        g + (size_t)(grp * 8 + (lane >> 3)) * ld + k0 + gchunk * 8;
    __builtin_amdgcn_global_load_lds(
        (const __attribute__((address_space(1))) unsigned int*)gp,
        (__attribute__((address_space(3))) unsigned int*)(lds + grp * 512),
        16, 0, 0);
  }
}

__device__ __forceinline__ void mfma_loop64(
    const unsigned short* __restrict__ A, int lda,
    const unsigned short* __restrict__ Bt, int ldb, int K,
    unsigned short* As, unsigned short* Bs, f32x4 acc[4][4],
    int wave, int lane) {
  const int wx = wave & 1, wy = wave >> 1;
  const int quad = lane >> 4, l16 = lane & 15;
  for (int k0 = 0; k0 < K; k0 += 64) {
    stage64(A, lda, k0, As, wave, lane);
    stage64(Bt, ldb, k0, Bs, wave, lane);
    __syncthreads();
#pragma unroll
    for (int h = 0; h < 2; ++h) {
      const int slot = ((((h << 2) | quad) ^ (l16 & 7))) * 8;
      short8 afr[4], bfr[4];
#pragma unroll
      for (int mt = 0; mt < 4; ++mt)
        afr[mt] = *(const short8*)&As[(wy * 64 + mt * 16 + l16) * 64 + slot];
#pragma unroll
      for (int nt = 0; nt < 4; ++nt)
        bfr[nt] = *(const short8*)&Bs[(wx * 64 + nt * 16 + l16) * 64 + slot];
#pragma unroll
      for (int mt = 0; mt < 4; ++mt)
#pragma unroll
        for (int nt = 0; nt < 4; ++nt)
          acc[mt][nt] = MFMA16(afr[mt], bfr[nt], acc[mt][nt]);
    }
    __syncthreads();
  }
}

// Projection epilogue for the 128x128 engine (slice-routed bf16 write).
__device__ __forceinline__ void proj_epilogue(
    f32x4 acc[4][4], const float* __restrict__ bias,
    unsigned short* __restrict__ Y, unsigned short* __restrict__ vTd,
    int c0, int m0, int lastSlice, int trans, int wave, int lane) {
  const int wx = wave & 1, wy = wave >> 1;
  const int quad = lane >> 4, l16 = lane & 15;
  const int slice = c0 / 768;
  if (trans && slice == lastSlice) {
#pragma unroll
    for (int mt = 0; mt < 4; ++mt) {
      const int row0 = m0 + wy * 64 + mt * 16 + quad * 4;
      const int b = row0 >> 10, n0 = row0 & 1023;
#pragma unroll
      for (int nt = 0; nt < 4; ++nt) {
        const int gcol = c0 + wx * 64 + nt * 16 + l16;
        const int d = gcol - slice * 768;
        const float bv = bias[gcol];
        uint2 o;
        o.x = (unsigned)f2bf(acc[mt][nt][0] + bv) |
              ((unsigned)f2bf(acc[mt][nt][1] + bv) << 16);
        o.y = (unsigned)f2bf(acc[mt][nt][2] + bv) |
              ((unsigned)f2bf(acc[mt][nt][3] + bv) << 16);
        *(uint2*)&vTd[((size_t)b * CDIM + d) * MDIM + n0] = o;
      }
    }
  } else {
    const size_t sbase = (size_t)slice * ROWS * 768;
#pragma unroll
    for (int mt = 0; mt < 4; ++mt)
#pragma unroll
      for (int nt = 0; nt < 4; ++nt) {
        const int gcol = c0 + wx * 64 + nt * 16 + l16;
        const int lcol = gcol - slice * 768;
        const float bv = bias[gcol];
#pragma unroll
        for (int rg = 0; rg < 4; ++rg) {
          const int row = m0 + wy * 64 + mt * 16 + quad * 4 + rg;
          Y[sbase + (size_t)row * 768 + lcol] = f2bf(acc[mt][nt][rg] + bv);
        }
      }
  }
}

// XCD-swizzled block mapping for (gx, 64) 128x128 grids.
__device__ __forceinline__ void swizzle_mc(int lin, int* m0, int* c0) {
  const int xcd = lin & 7, j = lin >> 3;
  *m0 = (xcd * 8 + (j & 7)) * 128;
  *c0 = (j >> 3) * 128;
}

// ---------------------------------------------------------------------------
// 256x256 engine, register-pipelined: 4 phases per K-tile, one barrier per
// phase, and each phase issues the ds_reads for the NEXT phase's MFMA while
// running this phase's MFMA on registers loaded last phase. MFMA thus never
// drains a fresh lgkmcnt(0); counted lgkm waits (4/8) drain only the
// previous phase's reads. This de-synchronizes the CU-wide LDS-read pipe
// (~1.9k cyc/K-tile) from the CU-wide MFMA pipe (~2.5k cyc/K-tile), which
// the phase-synchronous variants serialized (measured 6.4k cyc/K-tile,
// MfmaUtil 30%).
//
// Register sets: afrE (A-half for gm=0), afrO (A-half for gm=1), b0r, b1r.
// Steady phase p of K-tile t (bufc=buf[t&1], bufn=buf[(t+1)&1]):
//   P0: rd b1r<-B1(t)@bufc;  st A1(t+1)->bufn; vm8 BAR lgkm4; MFMA(0,0)[afrE,b0r]
//   P1: rd afrO<-A1(t)@bufc; st A0(t+2)->bufc; vm8 BAR lgkm8; MFMA(0,1)[afrE,b1r]
//   P2: rd afrE<-A0(t+1)@bufn; st B0(t+2)->bufc; vm8 BAR lgkm8; MFMA(1,0)[afrO,b0r]
//   P3: rd b0r<-B0(t+1)@bufn;  st B1(t+2)->bufc; vm8 BAR lgkm4; MFMA(1,1)[afrO,b1r]
//
// vmcnt(8) before each BAR: 4 halves (8 loads/thread) in flight; the half
// needed by the NEXT phase's read is always older than the newest 8, and the
// barrier publishes every wave's wait to the readers of its staged rows.
// lgkm ledger (reads outstanding before wait -> after): P0:12->4, P1:12->8,
// P2:16->8, P3:12->4 — each MFMA's operands are proven drained.
// Clobber safety: each stage's target slot had its last read drained one
// lgkm earlier and >=1 barrier separates that drain from the stage issue.
// Tails t=10/11 peeled with decaying vmcnt (6/4/2/0) and final lgkm(0).
// ---------------------------------------------------------------------------
__device__ __forceinline__ void stage_half256(
    const unsigned short* __restrict__ g, int k0,
    unsigned short* lds, int wave, int lane) {
  const int gchunk = (lane & 7) ^ (lane >> 3);
#pragma unroll
  for (int j = 0; j < 2; ++j) {
    const int grp = wave * 2 + j;
    const unsigned short* gp =
        g + (size_t)(grp * 8 + (lane >> 3)) * CDIM + k0 + gchunk * 8;
    __builtin_amdgcn_global_load_lds(
        (const __attribute__((address_space(1))) unsigned int*)gp,
        (__attribute__((address_space(3))) unsigned int*)(lds + grp * 512),
        16, 0, 0);
  }
}

__device__ __forceinline__ void read_fragsA(
    const unsigned short* h, int roff, short8 fr[4][2], int l16, int quad) {
#pragma unroll
  for (int mf = 0; mf < 4; ++mf)
#pragma unroll
    for (int kh = 0; kh < 2; ++kh) {
      const int slot = (((kh << 2) | quad) ^ (l16 & 7)) * 8;
      fr[mf][kh] = *(const short8*)&h[(roff + mf * 16 + l16) * 64 + slot];
    }
}

__device__ __forceinline__ void read_fragsB(
    const unsigned short* h, int roff, short8 fr[2][2], int l16, int quad) {
#pragma unroll
  for (int nf = 0; nf < 2; ++nf)
#pragma unroll
    for (int kh = 0; kh < 2; ++kh) {
      const int slot = (((kh << 2) | quad) ^ (l16 & 7)) * 8;
      fr[nf][kh] = *(const short8*)&h[(roff + nf * 16 + l16) * 64 + slot];
    }
}

#define MFMA_PHASE(GM, GN, AA, BB)                                          \
  do {                                                                      \
    SCHED_FENCE();                                                          \
    __builtin_amdgcn_s_setprio(1);                                          \
    _Pragma("unroll") for (int mf = 0; mf < 4; ++mf)                        \
    _Pragma("unroll") for (int nf = 0; nf < 2; ++nf)                        \
    _Pragma("unroll") for (int kh = 0; kh < 2; ++kh)                        \
        acc[GM][GN][mf][nf] =                                               \
            MFMA16(AA[mf][kh], BB[nf][kh], acc[GM][GN][mf][nf]);            \
    __builtin_amdgcn_s_setprio(0);                                          \
    SCHED_FENCE();                                                          \
  } while (0)

// Combined qkv (layout_x@Wqkv, 288 blocks) + kv (text_x@Wkv, 192 blocks):
// both K=768, equal-cost blocks, 480 total = 94%-balanced 2 rounds.
// Last 768-slice of each is written transposed into vTd[b][d][n].
__global__ __launch_bounds__(512, 2) void gemm_qkvkv(
    const unsigned short* __restrict__ A0g, const unsigned short* __restrict__ B0g,
    const float* __restrict__ bias0, unsigned short* __restrict__ Y0,
    unsigned short* __restrict__ vT0,
    const unsigned short* __restrict__ A1g, const unsigned short* __restrict__ B1g,
    const float* __restrict__ bias1, unsigned short* __restrict__ Y1,
    unsigned short* __restrict__ vT1) {
  __shared__ __align__(16) unsigned short lds[65536];  // 128 KiB
  int lin = blockIdx.x;
  const unsigned short *A, *Bt; const float* bias;
  unsigned short *Y, *vTd; int lastSlice, m0, c0;
  if (lin < 288) {            // qkv: 32 m-tiles x 9 c-tiles
    A = A0g; Bt = B0g; bias = bias0; Y = Y0; vTd = vT0; lastSlice = 2;
    const int xcd = lin & 7, j = lin >> 3;          // j in [0,36)
    m0 = (xcd * 4 + (j & 3)) * 256; c0 = (j >> 2) * 256;
  } else {                    // kv: 32 m-tiles x 6 c-tiles
    lin -= 288;
    A = A1g; Bt = B1g; bias = bias1; Y = Y1; vTd = vT1; lastSlice = 1;
    const int xcd = lin & 7, j = lin >> 3;          // j in [0,24)
    m0 = (xcd * 4 + (j & 3)) * 256; c0 = (j >> 2) * 256;
  }
  const int tid = threadIdx.x;
  const int wave = tid >> 6, lane = tid & 63;
  const int wy = wave >> 2, wx = wave & 3;          // 2 x 4 waves
  const int quad = lane >> 4, l16 = lane & 15;

  const unsigned short* Ah[2] = {A + (size_t)m0 * CDIM,
                                 A + (size_t)(m0 + 128) * CDIM};
  const unsigned short* Bh[2] = {Bt + (size_t)c0 * CDIM,
                                 Bt + (size_t)(c0 + 128) * CDIM};

  const f32x4 vzero = {0.f, 0.f, 0.f, 0.f};
  f32x4 acc[2][2][4][2];
#pragma unroll
  for (int gm = 0; gm < 2; ++gm)
#pragma unroll
    for (int gn = 0; gn < 2; ++gn)
#pragma unroll
      for (int mf = 0; mf < 4; ++mf)
#pragma unroll
        for (int nf = 0; nf < 2; ++nf) acc[gm][gn][mf][nf] = vzero;
  short8 afrE[4][2], afrO[4][2], b0r[2][2], b1r[2][2];

  // Prologue: stage buf0{A0,B0,B1,A1}(0) + buf1{A0,B0,B1}(1) = 14 loads;
  // vmcnt(8) lands the 6 oldest (A0,B0,B1 of t=0); BAR publishes; then read
  // the t=0 P0 operands (afrE<-A0(0), b0r<-B0(0)), drained by P0's lgkm4.
  stage_half256(Ah[0], 0, lds + 0, wave, lane);
  stage_half256(Bh[0], 0, lds + 16384, wave, lane);
  stage_half256(Bh[1], 0, lds + 24576, wave, lane);
  stage_half256(Ah[1], 0, lds + 8192, wave, lane);
  stage_half256(Ah[0], 64, lds + 32768 + 0, wave, lane);
  stage_half256(Bh[0], 64, lds + 32768 + 16384, wave, lane);
  stage_half256(Bh[1], 64, lds + 32768 + 24576, wave, lane);
  WAIT_VM8();
  BAR(); FENCE();
  read_fragsA(lds + 0, wy * 64, afrE, l16, quad);
  read_fragsB(lds + 16384, wx * 32, b0r, l16, quad);

  for (int t = 0; t < 10; ++t) {
    unsigned short* bufc = lds + (t & 1) * 32768;
    unsigned short* bufn = lds + ((t + 1) & 1) * 32768;
    // ---- P0 ----
    read_fragsB(bufc + 24576, wx * 32, b1r, l16, quad);
    stage_half256(Ah[1], (t + 1) * 64, bufn + 8192, wave, lane);
    WAIT_VM8(); BAR(); WAIT_LGKM4();
    MFMA_PHASE(0, 0, afrE, b0r);
    // ---- P1 ----
    read_fragsA(bufc + 8192, wy * 64, afrO, l16, quad);
    stage_half256(Ah[0], (t + 2) * 64, bufc + 0, wave, lane);
    WAIT_VM8(); BAR(); WAIT_LGKM8();
    MFMA_PHASE(0, 1, afrE, b1r);
    // ---- P2 ----
    read_fragsA(bufn + 0, wy * 64, afrE, l16, quad);
    stage_half256(Bh[0], (t + 2) * 64, bufc + 16384, wave, lane);
    WAIT_VM8(); BAR(); WAIT_LGKM8();
    MFMA_PHASE(1, 0, afrO, b0r);
    // ---- P3 ----
    read_fragsB(bufn + 16384, wx * 32, b0r, l16, quad);
    stage_half256(Bh[1], (t + 2) * 64, bufc + 24576, wave, lane);
    WAIT_VM8(); BAR(); WAIT_LGKM4();
    MFMA_PHASE(1, 1, afrO, b1r);
  }
  // ---- t = 10: only A1(11) still stages; vmcnt decays 8/6/4/2 ----
  {
    unsigned short* bufc = lds + 0;
    unsigned short* bufn = lds + 32768;
    read_fragsB(bufc + 24576, wx * 32, b1r, l16, quad);
    stage_half256(Ah[1], 11 * 64, bufn + 8192, wave, lane);
    WAIT_VM8(); BAR(); WAIT_LGKM4();
    MFMA_PHASE(0, 0, afrE, b0r);

    read_fragsA(bufc + 8192, wy * 64, afrO, l16, quad);
    WAIT_VM6(); BAR(); WAIT_LGKM8();
    MFMA_PHASE(0, 1, afrE, b1r);

    read_fragsA(bufn + 0, wy * 64, afrE, l16, quad);
    WAIT_VM4(); BAR(); WAIT_LGKM8();
    MFMA_PHASE(1, 0, afrO, b0r);

    read_fragsB(bufn + 16384, wx * 32, b0r, l16, quad);
    WAIT_VM2(); BAR(); WAIT_LGKM4();
    MFMA_PHASE(1, 1, afrO, b1r);
  }
  // ---- t = 11: all data in buf1; no stages; barriers only where needed ----
  {
    unsigned short* bufc = lds + 32768;
    read_fragsB(bufc + 24576, wx * 32, b1r, l16, quad);
    WAIT_VM0(); BAR(); WAIT_LGKM4();
    MFMA_PHASE(0, 0, afrE, b0r);

    read_fragsA(bufc + 8192, wy * 64, afrO, l16, quad);
    WAIT_LGKM8();
    MFMA_PHASE(0, 1, afrE, b1r);

    WAIT_LGKM0();
    MFMA_PHASE(1, 0, afrO, b0r);
    MFMA_PHASE(1, 1, afrO, b1r);
  }

  // Epilogue: slice-routed writes (last slice transposed to vTd[b][d][n]).
#pragma unroll
  for (int gm = 0; gm < 2; ++gm)
#pragma unroll
    for (int gn = 0; gn < 2; ++gn) {
      const int cb2 = c0 + gn * 128 + wx * 32;
      const int slice = cb2 / 768;
      const int rb = m0 + gm * 128 + wy * 64;
      if (slice == lastSlice) {
#pragma unroll
        for (int mf = 0; mf < 4; ++mf) {
          const int row0 = rb + mf * 16 + quad * 4;
          const int b = row0 >> 10, n0 = row0 & 1023;
#pragma unroll
          for (int nf = 0; nf < 2; ++nf) {
            const int gcol = cb2 + nf * 16 + l16;
            const int d = gcol - slice * 768;
            const float bv = bias[gcol];
            uint2 o;
            o.x = (unsigned)f2bf(acc[gm][gn][mf][nf][0] + bv) |
                  ((unsigned)f2bf(acc[gm][gn][mf][nf][1] + bv) << 16);
            o.y = (unsigned)f2bf(acc[gm][gn][mf][nf][2] + bv) |
                  ((unsigned)f2bf(acc[gm][gn][mf][nf][3] + bv) << 16);
            *(uint2*)&vTd[((size_t)b * CDIM + d) * MDIM + n0] = o;
          }
        }
      } else {
        const size_t sbase = (size_t)slice * ROWS * 768;
#pragma unroll
        for (int mf = 0; mf < 4; ++mf)
#pragma unroll
          for (int nf = 0; nf < 2; ++nf) {
            const int gcol = cb2 + nf * 16 + l16;
            const int lcol = gcol - slice * 768;
            const float bv = bias[gcol];
#pragma unroll
            for (int rg = 0; rg < 4; ++rg) {
              const int row = rb + mf * 16 + quad * 4 + rg;
              Y[sbase + (size_t)row * 768 + lcol] =
                  f2bf(acc[gm][gn][mf][nf][rg] + bv);
            }
          }
      }
    }
}

// ---------------------------------------------------------------------------
// cq / FFN projections on the 128x128 engine.
// ---------------------------------------------------------------------------
__global__ __launch_bounds__(256, 4) void gemm_proj(
    const unsigned short* __restrict__ A, const unsigned short* __restrict__ Bt,
    const float* __restrict__ bias, unsigned short* __restrict__ Y,
    unsigned short* __restrict__ vTd, int trans) {
  __shared__ __align__(16) unsigned short As[128 * 64];
  __shared__ __align__(16) unsigned short Bs[128 * 64];
  int m0, c0;
  swizzle_mc(blockIdx.y * gridDim.x + blockIdx.x, &m0, &c0);
  const int tid = threadIdx.x;
  const int wave = tid >> 6, lane = tid & 63;
  const f32x4 vzero = {0.f, 0.f, 0.f, 0.f};
  f32x4 acc[4][4];
#pragma unroll
  for (int mt = 0; mt < 4; ++mt)
#pragma unroll
    for (int nt = 0; nt < 4; ++nt) acc[mt][nt] = vzero;
  mfma_loop64(A + (size_t)m0 * CDIM, CDIM, Bt + (size_t)c0 * CDIM, CDIM, CDIM,
              As, Bs, acc, wave, lane);
  proj_epilogue(acc, bias, Y, vTd, c0, m0, (int)(gridDim.x / 6) - 1, trans,
                wave, lane);
}

__global__ __launch_bounds__(256, 4) void gemm_ffn(
    const unsigned short* __restrict__ A, const unsigned short* __restrict__ Bt,
    const float* __restrict__ bias, float* __restrict__ Y) {
  __shared__ __align__(16) unsigned short As[128 * 64];
  __shared__ __align__(16) unsigned short Bs[128 * 64];
  int m0, c0;
  swizzle_mc(blockIdx.y * gridDim.x + blockIdx.x, &m0, &c0);
  const int tid = threadIdx.x;
  const int wave = tid >> 6, lane = tid & 63;
  const int wx = wave & 1, wy = wave >> 1;
  const int quad = lane >> 4, l16 = lane & 15;
  const f32x4 vzero = {0.f, 0.f, 0.f, 0.f};
  f32x4 acc[4][4];
#pragma unroll
  for (int mt = 0; mt < 4; ++mt)
#pragma unroll
    for (int nt = 0; nt < 4; ++nt) acc[mt][nt] = vzero;
  mfma_loop64(A + (size_t)m0 * CDIM, CDIM, Bt + (size_t)c0 * CDIM, CDIM, CDIM,
              As, Bs, acc, wave, lane);
#pragma unroll
  for (int mt = 0; mt < 4; ++mt)
#pragma unroll
    for (int nt = 0; nt < 4; ++nt) {
      const int col = c0 + wx * 64 + nt * 16 + l16;
      const float bv = bias[col];
#pragma unroll
      for (int rg = 0; rg < 4; ++rg) {
        const int row = m0 + wy * 64 + mt * 16 + quad * 4 + rg;
        Y[(size_t)row * 768 + col] = acc[mt][nt][rg] + bv;
      }
    }
}

// ---------------------------------------------------------------------------
// Batched QK^T with fused exp + row-sum: S[b] = exp(scale*QK^T) (masked ->
// 1e-30f). Row sums stored as race-free partials per (cblock, wx):
// rsp[((cb*2+wx)*8 + b)*1024 + row]  (16 partials per row, no atomics,
// no zero-init needed). grid (8,8,BDIM).
// ---------------------------------------------------------------------------
__global__ __launch_bounds__(256, 4) void gemm_qk(
    const unsigned short* __restrict__ Qb, const unsigned short* __restrict__ Kb,
    const float* __restrict__ mask, unsigned short* __restrict__ S, float scale,
    float* __restrict__ rsp) {
  __shared__ __align__(16) unsigned short As[128 * 64];
  __shared__ __align__(16) unsigned short Bs[128 * 64];
  const int c0 = blockIdx.x * 128;
  const int m0 = blockIdx.y * 128;
  const int b = blockIdx.z;
  const int tid = threadIdx.x;
  const int wave = tid >> 6, lane = tid & 63;
  const int wx = wave & 1, wy = wave >> 1;
  const int quad = lane >> 4, l16 = lane & 15;

  const f32x4 vzero = {0.f, 0.f, 0.f, 0.f};
  f32x4 acc[4][4];
#pragma unroll
  for (int mt = 0; mt < 4; ++mt)
#pragma unroll
    for (int nt = 0; nt < 4; ++nt) acc[mt][nt] = vzero;

  mfma_loop64(Qb + ((size_t)b * MDIM + m0) * CDIM, CDIM,
              Kb + ((size_t)b * MDIM + c0) * CDIM, CDIM, CDIM,
              As, Bs, acc, wave, lane);

  const float* maskb = mask + b * MDIM;
  float mrow[4][4], rsum[4][4];
#pragma unroll
  for (int mt = 0; mt < 4; ++mt)
#pragma unroll
    for (int rg = 0; rg < 4; ++rg) {
      mrow[mt][rg] = maskb[m0 + wy * 64 + mt * 16 + quad * 4 + rg];
      rsum[mt][rg] = 0.f;
    }
  unsigned short* Sb = S + (size_t)b * MDIM * MDIM;
#pragma unroll
  for (int nt = 0; nt < 4; ++nt) {
    const int col = c0 + wx * 64 + nt * 16 + l16;
    const float mcol = maskb[col];
#pragma unroll
    for (int mt = 0; mt < 4; ++mt)
#pragma unroll
      for (int rg = 0; rg < 4; ++rg) {
        const int row = m0 + wy * 64 + mt * 16 + quad * 4 + rg;
        const float e = (mrow[mt][rg] * mcol != 0.f)
                            ? __expf(acc[mt][nt][rg] * scale)
                            : 1e-30f;
        Sb[(size_t)row * MDIM + col] = f2bf(e);
        rsum[mt][rg] += e;
      }
  }
  // reduce across the 16 lanes of each quad (they share rows)
  for (int off = 1; off < 16; off <<= 1) {
#pragma unroll
    for (int mt = 0; mt < 4; ++mt)
#pragma unroll
      for (int rg = 0; rg < 4; ++rg)
        rsum[mt][rg] += __shfl_xor(rsum[mt][rg], off, 64);
  }
  if (l16 == 0) {
    float* rs = rsp + ((((size_t)blockIdx.x * 2 + wx) * 8 + b) << 10) +
                m0 + wy * 64;
#pragma unroll
    for (int mt = 0; mt < 4; ++mt)
#pragma unroll
      for (int rg = 0; rg < 4; ++rg)
        rs[mt * 16 + quad * 4 + rg] = rsum[mt][rg];
  }
}

// ---------------------------------------------------------------------------
// O = (unnormalized P) @ V, normalized by 1/rowsum per row. rowsum = sum of
// 16 partials (lane l16 loads partial p=l16, 16-lane shuffle reduce).
// grid (6, 8, BDIM).
// ---------------------------------------------------------------------------
__global__ __launch_bounds__(256, 4) void attn_pv(
    const unsigned short* __restrict__ P, const unsigned short* __restrict__ vT,
    unsigned short* __restrict__ O, const float* __restrict__ rsp) {
  __shared__ __align__(16) unsigned short As[128 * 64];
  __shared__ __align__(16) unsigned short Bs[128 * 64];
  const int c0 = blockIdx.x * 128;
  const int m0 = blockIdx.y * 128;
  const int b = blockIdx.z;
  const int tid = threadIdx.x;
  const int wave = tid >> 6, lane = tid & 63;
  const int wx = wave & 1, wy = wave >> 1;
  const int quad = lane >> 4, l16 = lane & 15;

  const f32x4 vzero = {0.f, 0.f, 0.f, 0.f};
  f32x4 acc[4][4];
#pragma unroll
  for (int mt = 0; mt < 4; ++mt)
#pragma unroll
    for (int nt = 0; nt < 4; ++nt) acc[mt][nt] = vzero;

  mfma_loop64(P + ((size_t)b * MDIM + m0) * MDIM, MDIM,
              vT + ((size_t)b * CDIM + c0) * MDIM, MDIM, MDIM,
              As, Bs, acc, wave, lane);

  const float* rsb = rsp + (((size_t)l16 * 8 + b) << 10) + m0 + wy * 64;
  float inv[4][4];
#pragma unroll
  for (int mt = 0; mt < 4; ++mt)
#pragma unroll
    for (int rg = 0; rg < 4; ++rg) {
      float s = rsb[mt * 16 + quad * 4 + rg];
      for (int off = 1; off < 16; off <<= 1) s += __shfl_xor(s, off, 64);
      inv[mt][rg] = 1.f / s;
    }
#pragma unroll
  for (int mt = 0; mt < 4; ++mt)
#pragma unroll
    for (int nt = 0; nt < 4; ++nt)
#pragma unroll
      for (int rg = 0; rg < 4; ++rg) {
        const int row = m0 + wy * 64 + mt * 16 + quad * 4 + rg;
        const int col = c0 + wx * 64 + nt * 16 + l16;
        O[(size_t)(b * MDIM + row) * CDIM + col] =
            f2bf(acc[mt][nt][rg] * inv[mt][rg]);
      }
}

// ---------------------------------------------------------------------------
extern "C" void kernel_launch(void* const* d_in, const int* in_sizes, int n_in,
                              void* d_out, int out_size, void* d_ws, size_t ws_size,
                              hipStream_t stream) {
  const float* layout_x = (const float*)d_in[0];
  const float* text_x   = (const float*)d_in[1];
  const float* maskp    = (const float*)d_in[2];
  const float* Wqkv     = (const float*)d_in[3];
  const float* bqkv     = (const float*)d_in[4];
  const float* Wq       = (const float*)d_in[5];
  const float* bq       = (const float*)d_in[6];
  const float* Wkv      = (const float*)d_in[7];
  const float* bkv      = (const float*)d_in[8];
  const float* Wffn     = (const float*)d_in[9];
  const float* bffn     = (const float*)d_in[10];
  float* out = (float*)d_out;
  char* ws = (char*)d_ws;

  const float scale = 1.0f / sqrtf((float)CDIM);

  // ---- workspace (bytes), live total 87,949,312 ----
  unsigned short* xlb    = (unsigned short*)(ws);              // -> attn1/merge
  unsigned short* xtb    = (unsigned short*)(ws + 12582912);   // dead after proj -> rsp
  unsigned short* Wqkv_t = (unsigned short*)(ws + 25165824);
  unsigned short* Wq_t   = (unsigned short*)(ws + 28704768);
  unsigned short* Wkv_t  = (unsigned short*)(ws + 29884416);
  unsigned short* Wffn_t = (unsigned short*)(ws + 32243712);
  unsigned short* Qb     = (unsigned short*)(ws + 33423360);   // slice1=K contiguous
  unsigned short* Kb     = (unsigned short*)(ws + 46006272);
  unsigned short* vT     = (unsigned short*)(ws + 58589184);   // V^T
  unsigned short* S      = (unsigned short*)(ws + 71172096);   // 16.8 MB
  unsigned short* attn1  = xlb;
  unsigned short* cqb    = Qb;           // Qb dead after qk1
  // cross-attention K / V^T live in d_out (exactly 2 x 12,582,912 B);
  // ffn overwrites out only after pv2 consumed them.
  unsigned short* cK  = (unsigned short*)out;
  unsigned short* cVT = (unsigned short*)out + 6291456;
  // rowsum partials (512 KB) in the xtb region (dead after gemm_qkvkv).
  float* rsp = (float*)xtb;

  // 1) prologue: input converts + weight transposes
  prologue<<<10176, 256, 0, stream>>>(layout_x, text_x, xlb, xtb,
                                      Wqkv, Wq, Wkv, Wffn,
                                      Wqkv_t, Wq_t, Wkv_t, Wffn_t);
  // 2) combined 256^2 engine: {Q,K -> Qb,Kb; V -> vT^T} + {cK -> out; cV -> cVT^T}
  gemm_qkvkv<<<480, 512, 0, stream>>>(xlb, Wqkv_t, bqkv, Qb, vT,
                                      xtb, Wkv_t, bkv, cK, cVT);
  // 3) S = exp(scale*QK^T) masked; rowsum partials
  gemm_qk<<<dim3(8, 8, BDIM), 256, 0, stream>>>(Qb, Kb, maskp, S, scale, rsp);
  // 4) attn1 = bf16((S @ V) / rowsum)
  attn_pv<<<dim3(6, 8, BDIM), 256, 0, stream>>>(S, vT, attn1, rsp);
  // 5) cq = attn1@Wq+bq
  gemm_proj<<<dim3(6, 64), 256, 0, stream>>>(attn1, Wq_t, bq, cqb, vT, 0);
  // 6) S = exp(scale*cq cK^T) masked; rowsum partials
  gemm_qk<<<dim3(8, 8, BDIM), 256, 0, stream>>>(cqb, cK, maskp, S, scale, rsp);
  // 7) merge = bf16((S @ cV) / rowsum)
  attn_pv<<<dim3(6, 8, BDIM), 256, 0, stream>>>(S, cVT, attn1, rsp);
  // 8) out = merge @ Wffn + bffn (f32)
  gemm_ffn<<<dim3(6, 64), 256, 0, stream>>>(attn1, Wffn_t, bffn, out);
}